// Round 5
// baseline (369.009 us; speedup 1.0000x reference)
//
#include <hip/hip_runtime.h>

// Problem constants (from reference) — ALL TENSORS ARE FLOAT32.
#define NPP   64
#define NRR   8
#define NKK   500
#define HDIM  256
#define NHEAD 8
#define VDIM  8
#define HD    32
#define BTOT  512   // NPP*NRR

// ---- fast transcendentals (hardware v_exp_f32 / v_rcp_f32) ----
__device__ __forceinline__ float fast_tanh(float x) {
  const float e = __expf(2.f * x);
  return 1.f - 2.f * __builtin_amdgcn_rcpf(e + 1.f);
}
__device__ __forceinline__ float fast_sig(float x) {
  return __builtin_amdgcn_rcpf(1.f + __expf(-x));
}

// keep-live pins: force loads to issue early / complete here (rule #17)
#define PIN1(x)  asm volatile("" :: "v"(x))
#define PIN4(v)  asm volatile("" :: "v"((v).x), "v"((v).y), "v"((v).z), "v"((v).w))

// ===========================================================================
// Kernel 1: LSTM cell, tiled GEMM, 32 gate-rows x 32 batch tiles, 256 thr
// (round-0 proven config).  Block (0,0) probes the mask dtype into ws flag
// and zeroes the 128 cross-block counters used by attn/logits folds.
// ===========================================================================
__global__ __launch_bounds__(256) void k_lstm3(
    const float* __restrict__ query, const float* __restrict__ state1,
    const float* __restrict__ state2,
    const float* __restrict__ W_ih, const float* __restrict__ W_hh,
    const float* __restrict__ b_ih, const float* __restrict__ b_hh,
    const unsigned char* __restrict__ maskb, int* __restrict__ flagp,
    int* __restrict__ cnts,
    float* __restrict__ out_h, float* __restrict__ out_c)
{
  __shared__ float Wt[32][33];
  __shared__ float At[32][33];
  __shared__ float gt[32][33];

  const int t  = threadIdx.x;
  const int hb = blockIdx.x;
  const int bb = blockIdx.y;

  if (flagp != nullptr && hb == 0 && bb == 0) {
    __shared__ int f;
    if (t == 0) f = 0;
    if (cnts != nullptr && t < 128) cnts[t] = 0;
    __syncthreads();
    int any = 0;
    for (int j = t; j < 2048; j += 256) any |= maskb[2 * j + 1];
    if (any) atomicOr(&f, 1);
    __syncthreads();
    if (t == 0) *flagp = f;
  }

  const int trow = t >> 4;
  const int tcol = t & 15;

  float acc00 = 0.f, acc01 = 0.f, acc10 = 0.f, acc11 = 0.f;

  const int wrow = t >> 3, wk4 = t & 7;
  const int wpart = wrow >> 3, whh = wrow & 7;
  const int wgrow = wpart * HDIM + hb * 8 + whh;
  const int agrow = bb * 32 + wrow;

  for (int k0 = 0; k0 < 512; k0 += 32) {
    __syncthreads();
    {
      const float* wsrc = (k0 < 256) ? (W_ih + (size_t)wgrow * HDIM + k0)
                                     : (W_hh + (size_t)wgrow * HDIM + (k0 - 256));
      const float4 wv = *reinterpret_cast<const float4*>(wsrc + wk4 * 4);
      Wt[wk4 * 4 + 0][wrow] = wv.x; Wt[wk4 * 4 + 1][wrow] = wv.y;
      Wt[wk4 * 4 + 2][wrow] = wv.z; Wt[wk4 * 4 + 3][wrow] = wv.w;

      const float* asrc = (k0 < 256) ? (query  + (size_t)agrow * HDIM + k0)
                                     : (state1 + (size_t)agrow * HDIM + (k0 - 256));
      const float4 av = *reinterpret_cast<const float4*>(asrc + wk4 * 4);
      At[wk4 * 4 + 0][wrow] = av.x; At[wk4 * 4 + 1][wrow] = av.y;
      At[wk4 * 4 + 2][wrow] = av.z; At[wk4 * 4 + 3][wrow] = av.w;
    }
    __syncthreads();

#pragma unroll 8
    for (int kk = 0; kk < 32; ++kk) {
      const float w0 = Wt[kk][trow], w1 = Wt[kk][trow + 16];
      const float a0 = At[kk][tcol], a1 = At[kk][tcol + 16];
      acc00 += w0 * a0; acc01 += w0 * a1;
      acc10 += w1 * a0; acc11 += w1 * a1;
    }
  }

  gt[trow][tcol] = acc00;      gt[trow][tcol + 16] = acc01;
  gt[trow + 16][tcol] = acc10; gt[trow + 16][tcol + 16] = acc11;
  __syncthreads();

  {
    const int h = t & 7, b = t >> 3;
    const int gh = hb * 8 + h;
    const int gb = bb * 32 + b;
    const float bi = b_ih[0 * HDIM + gh] + b_hh[0 * HDIM + gh];
    const float bf = b_ih[1 * HDIM + gh] + b_hh[1 * HDIM + gh];
    const float bg = b_ih[2 * HDIM + gh] + b_hh[2 * HDIM + gh];
    const float bo = b_ih[3 * HDIM + gh] + b_hh[3 * HDIM + gh];
    const float iv = fast_sig (gt[ 0 + h][b] + bi);
    const float fv = fast_sig (gt[ 8 + h][b] + bf);
    const float gv = fast_tanh(gt[16 + h][b] + bg);
    const float ov = fast_sig (gt[24 + h][b] + bo);
    const size_t off = (size_t)gb * HDIM + gh;
    const float c = fv * state2[off] + iv * gv;
    out_c[off] = c;
    out_h[off] = ov * fast_tanh(c);
  }
}

// ===========================================================================
// Kernel 2: attention per (p, head), 512 threads, VGPR cap 128.
// ALL long-latency loads (h, K, V, mask) issued at entry and PINNED so the
// compiler cannot sink them; nn_O issued 3 phases ahead.  After the slab
// write, the last of the 8 blocks for each p folds the slab-sum (+nn_B)
// into qbg (device-scope fence + atomic counter).
// ===========================================================================
__global__ __launch_bounds__(512, 4) void k_attn11(
    const float* __restrict__ Kt, const float* __restrict__ Vt,
    const float* __restrict__ nn_Q, const float* __restrict__ nn_O,
    const float* __restrict__ nn_B,
    const void* __restrict__ maskp, const int* __restrict__ flagp,
    int* __restrict__ cnta,
    const float* __restrict__ out_h, float* __restrict__ qm_slabs,
    float* __restrict__ qbg)
{
  const int p = blockIdx.x >> 3;
  const int a = blockIdx.x & 7;
  const int t = threadIdx.x;
  const int wave = t >> 6, lane = t & 63;

  __shared__ float hs[NRR][HDIM];       // 8 KB
  __shared__ float Qs[NRR][36];         // 1.2 KB
  __shared__ float Sb[NRR][512];        // 16 KB (cols 500..511 = -inf pad)
  __shared__ float pb[8][NRR][HD];      // 8 KB per-wave PV partials
  __shared__ float xs[NRR][36];         // 1.2 KB
  __shared__ int   lastf;

  // ---------- entry burst: h, K, V, mask all in flight -------------------
  const float4 hv = reinterpret_cast<const float4*>(
      out_h + (size_t)p * NRR * HDIM)[t];

  const int flag = *flagp;

  const int kc = (t < NKK) ? t : (NKK - 1);
  const float4* kp4 = reinterpret_cast<const float4*>(
      Kt + (((size_t)a * NPP + p) * NKK + kc) * HD);
  float4 kreg[8];
#pragma unroll
  for (int j = 0; j < 8; ++j) kreg[j] = kp4[j];

  const int kg = t >> 3;                // 0..63  k-group
  const int d4p = t & 7;                // f4 dim slot
  float4 v4[8];
  {
    const float* vbase = Vt + ((size_t)a * NPP + p) * NKK * HD + d4p * 4;
#pragma unroll
    for (int j = 0; j < 8; ++j) {
      const int k = kg + 64 * j;
      v4[j] = (k < NKK)
          ? *reinterpret_cast<const float4*>(vbase + (size_t)k * HD)
          : make_float4(0.f, 0.f, 0.f, 0.f);
    }
  }

  float maskv[NRR];
  {
    const unsigned char* mb = (const unsigned char*)maskp;
    const int* mi = (const int*)maskp;
#pragma unroll
    for (int r = 0; r < NRR; ++r) {
      const size_t mo = (size_t)(p * NRR + r) * NKK + kc;
      const bool mk = flag ? (mb[mo] != 0) : (mi[mo] != 0);
      maskv[r] = mk ? -INFINITY : 0.f;
    }
  }

  reinterpret_cast<float4*>(&hs[0][0])[t] = hv;

  // pin: loads must be issued by here; wait coincides with the hv barrier
#pragma unroll
  for (int j = 0; j < 8; ++j) { PIN4(kreg[j]); PIN4(v4[j]); }
#pragma unroll
  for (int r = 0; r < NRR; ++r) PIN1(maskv[r]);
  __syncthreads();

  // ---------- Q-proj: wave r; lane = (d4, ks); ks stride 4 ---------------
  {
    const int r = wave;
    const int d4 = lane >> 3, ks = lane & 7;
    float qx = 0.f, qy = 0.f, qz = 0.f, qw = 0.f;
#pragma unroll
    for (int i = 0; i < 8; ++i) {
      const int hb = 32 * i + ks * 4;
      const float4 hv4 = *reinterpret_cast<const float4*>(&hs[r][hb]);
      const float hh[4] = {hv4.x, hv4.y, hv4.z, hv4.w};
      const float* nqb = nn_Q + ((size_t)a * HDIM + hb) * HD + d4 * 4;
#pragma unroll
      for (int jj = 0; jj < 4; ++jj) {
        const float4 wv = *reinterpret_cast<const float4*>(nqb + (size_t)jj * HD);
        qx += hh[jj] * wv.x; qy += hh[jj] * wv.y;
        qz += hh[jj] * wv.z; qw += hh[jj] * wv.w;
      }
    }
#pragma unroll
    for (int off = 1; off < 8; off <<= 1) {
      qx += __shfl_xor(qx, off, 64);
      qy += __shfl_xor(qy, off, 64);
      qz += __shfl_xor(qz, off, 64);
      qw += __shfl_xor(qw, off, 64);
    }
    if (ks == 0) {
      const float sc = 0.17677669529663687f;   // 1/sqrt(32)
      Qs[r][d4 * 4 + 0] = qx * sc; Qs[r][d4 * 4 + 1] = qy * sc;
      Qs[r][d4 * 4 + 2] = qz * sc; Qs[r][d4 * 4 + 3] = qw * sc;
    }
  }
  __syncthreads();

  // ---------- scores from pinned kreg ------------------------------------
#pragma unroll
  for (int r = 0; r < NRR; ++r) {
    float s = 0.f;
#pragma unroll
    for (int j = 0; j < 8; ++j) {
      const float4 q = *reinterpret_cast<const float4*>(&Qs[r][j * 4]);
      const float4 k4 = kreg[j];
      s += q.x * k4.x + q.y * k4.y + q.z * k4.z + q.w * k4.w;
    }
    Sb[r][t] = (t < NKK) ? (s + maskv[r]) : -INFINITY;
  }

  // ---------- nn_O prefetch: 3 phases ahead of its use -------------------
  const int j8 = t & 255;
  float orr[32];
  {
    const float* ob = nn_O + (size_t)(a * HD) * HDIM + j8;
#pragma unroll
    for (int d = 0; d < 32; ++d) orr[d] = ob[(size_t)d * HDIM];
  }
  __syncthreads();

  // ---------- softmax: wave w -> rollout w -------------------------------
  {
    const int r = wave;
    float lv[8], m = -INFINITY;
#pragma unroll
    for (int i = 0; i < 8; ++i) {
      lv[i] = Sb[r][lane + 64 * i];
      m = fmaxf(m, lv[i]);
    }
#pragma unroll
    for (int off = 32; off > 0; off >>= 1) m = fmaxf(m, __shfl_xor(m, off, 64));
    float ssum = 0.f;
#pragma unroll
    for (int i = 0; i < 8; ++i) {
      lv[i] = __expf(lv[i] - m);
      ssum += lv[i];
    }
#pragma unroll
    for (int off = 32; off > 0; off >>= 1) ssum += __shfl_xor(ssum, off, 64);
    const float inv = 1.f / ssum;
#pragma unroll
    for (int i = 0; i < 8; ++i) Sb[r][lane + 64 * i] = lv[i] * inv;
  }
  __syncthreads();

  // ---------- PV: pinned V regs x Sb broadcasts; shfl-reduce over kg -----
  {
    float4 acc4[NRR];
#pragma unroll
    for (int r = 0; r < NRR; ++r) acc4[r] = make_float4(0.f, 0.f, 0.f, 0.f);
#pragma unroll
    for (int j = 0; j < 8; ++j) {
      const float4 v = v4[j];
#pragma unroll
      for (int r = 0; r < NRR; ++r) {
        const float s = Sb[r][kg + 64 * j];   // pad rows are exact 0
        acc4[r].x += s * v.x; acc4[r].y += s * v.y;
        acc4[r].z += s * v.z; acc4[r].w += s * v.w;
      }
    }
#pragma unroll
    for (int off = 8; off < 64; off <<= 1) {
#pragma unroll
      for (int r = 0; r < NRR; ++r) {
        acc4[r].x += __shfl_xor(acc4[r].x, off, 64);
        acc4[r].y += __shfl_xor(acc4[r].y, off, 64);
        acc4[r].z += __shfl_xor(acc4[r].z, off, 64);
        acc4[r].w += __shfl_xor(acc4[r].w, off, 64);
      }
    }
    if (lane < 8) {
#pragma unroll
      for (int r = 0; r < NRR; ++r)
        *reinterpret_cast<float4*>(&pb[wave][r][lane * 4]) = acc4[r];
    }
  }
  __syncthreads();

  if (t < 256) {
    const int r = t >> 5, d = t & 31;
    float s = 0.f;
#pragma unroll
    for (int w = 0; w < 8; ++w) s += pb[w][r][d];
    xs[r][d] = s;
  }
  __syncthreads();

  // ---------- O-proj from register-resident nn_O -> per-head slab --------
  {
    const int rr = t >> 8;                // row-group {0..3} or {4..7}
    float a0 = 0.f, a1 = 0.f, a2 = 0.f, a3 = 0.f;
#pragma unroll
    for (int d4 = 0; d4 < 8; ++d4) {
      const float4 x0 = *reinterpret_cast<const float4*>(&xs[rr * 4 + 0][d4 * 4]);
      const float4 x1 = *reinterpret_cast<const float4*>(&xs[rr * 4 + 1][d4 * 4]);
      const float4 x2 = *reinterpret_cast<const float4*>(&xs[rr * 4 + 2][d4 * 4]);
      const float4 x3 = *reinterpret_cast<const float4*>(&xs[rr * 4 + 3][d4 * 4]);
      const float c0[4] = {x0.x, x0.y, x0.z, x0.w};
      const float c1[4] = {x1.x, x1.y, x1.z, x1.w};
      const float c2[4] = {x2.x, x2.y, x2.z, x2.w};
      const float c3[4] = {x3.x, x3.y, x3.z, x3.w};
#pragma unroll
      for (int dd = 0; dd < 4; ++dd) {
        const float w = orr[d4 * 4 + dd];
        a0 += c0[dd] * w; a1 += c1[dd] * w;
        a2 += c2[dd] * w; a3 += c3[dd] * w;
      }
    }
    float* slab = qm_slabs + (size_t)a * BTOT * HDIM;
    slab[(size_t)(p * NRR + rr * 4 + 0) * HDIM + j8] = a0;
    slab[(size_t)(p * NRR + rr * 4 + 1) * HDIM + j8] = a1;
    slab[(size_t)(p * NRR + rr * 4 + 2) * HDIM + j8] = a2;
    slab[(size_t)(p * NRR + rr * 4 + 3) * HDIM + j8] = a3;
  }

  // ---------- last-block fold: qbg = sum_a slab[a] + nn_B ----------------
  __syncthreads();                        // all slab stores issued
  if (t == 0) {
    __threadfence();                      // publish slab writes
    lastf = (atomicAdd(&cnta[p], 1) == NHEAD - 1) ? 1 : 0;
  }
  __syncthreads();
  if (lastf) {
    __threadfence();                      // acquire other blocks' writes
    const int row = t >> 6, h4 = t & 63;  // 8 rows x 64 f4 slots
    float4 acc = *reinterpret_cast<const float4*>(nn_B + h4 * 4);
#pragma unroll
    for (int a2 = 0; a2 < NHEAD; ++a2) {
      const float4 q = *reinterpret_cast<const float4*>(
          qm_slabs + (size_t)a2 * BTOT * HDIM +
          (size_t)(p * NRR + row) * HDIM + h4 * 4);
      acc.x += q.x; acc.y += q.y; acc.z += q.z; acc.w += q.w;
    }
    *reinterpret_cast<float4*>(
        qbg + (size_t)(p * NRR + row) * HDIM + h4 * 4) = acc;
  }
}

// ===========================================================================
// Kernel 3: additive logits + per-(row, kt) softmax partials; the last of
// the 32 kt-blocks per p folds the final LSE: out_p = m - 10 - log(sum).
// Grid 64 x 32.  Wave owns 4 k; lane owns 4 h; zero LDS in the main loop.
// ===========================================================================
__global__ __launch_bounds__(256) void k_logits8(
    const float* __restrict__ X, const float* __restrict__ varfeat,
    const float* __restrict__ nn_A, const float* __restrict__ nn_W,
    const float* __restrict__ qbg,
    const int* __restrict__ flagp, const void* __restrict__ maskp,
    int* __restrict__ cntl,
    float* __restrict__ pmax, float* __restrict__ psum,
    float* __restrict__ out_p)
{
  const int p  = blockIdx.x >> 5;
  const int kt = blockIdx.x & 31;
  const int t = threadIdx.x;
  const int wave = t >> 6, lane = t & 63;
  const int h0 = lane * 4;

  __shared__ float red[4][NRR][2];      // per-wave (max, sum) partials
  __shared__ int   lastl;

  const unsigned char* mb = (const unsigned char*)maskp;
  const int* mi = (const int*)maskp;
  const int flag = *flagp;
  const bool mbyte = (flag != 0);

  const float4 w4 = *reinterpret_cast<const float4*>(nn_W + h0);
  float4 a4r[VDIM];
#pragma unroll
  for (int v = 0; v < VDIM; ++v)
    a4r[v] = *reinterpret_cast<const float4*>(nn_A + (size_t)v * HDIM + h0);
  float4 q4r[NRR];
#pragma unroll
  for (int r = 0; r < NRR; ++r)
    q4r[r] = *reinterpret_cast<const float4*>(
        qbg + (size_t)(p * NRR + r) * HDIM + h0);

  float rmax = -INFINITY, rsum = 0.f;    // valid at lanes with (lane&7)==0

  for (int kk = 0; kk < 4; ++kk) {
    const int k = kt * 16 + wave * 4 + kk;
    if (k >= NKK) break;   // wave-uniform

    const float4 x4 = *reinterpret_cast<const float4*>(
        X + ((size_t)p * NKK + k) * HDIM + h0);
    float base0 = x4.x, base1 = x4.y, base2 = x4.z, base3 = x4.w;
#pragma unroll
    for (int v = 0; v < VDIM; ++v) {
      const float vv = varfeat[((size_t)p * VDIM + v) * NKK + k];
      base0 += vv * a4r[v].x; base1 += vv * a4r[v].y;
      base2 += vv * a4r[v].z; base3 += vv * a4r[v].w;
    }

    float acc[NRR];
#pragma unroll
    for (int r = 0; r < NRR; ++r) {
      acc[r] = fast_tanh(base0 + q4r[r].x) * w4.x
             + fast_tanh(base1 + q4r[r].y) * w4.y
             + fast_tanh(base2 + q4r[r].z) * w4.z
             + fast_tanh(base3 + q4r[r].w) * w4.w;
    }

    // multi-value wave reduction: 8 sums across 64 lanes
    float v4r[4];
    {
      float sw[8];
#pragma unroll
      for (int j = 0; j < 8; ++j) sw[j] = __shfl_xor(acc[j], 32, 64);
      const bool hi = (lane & 32) != 0;
#pragma unroll
      for (int j = 0; j < 4; ++j)
        v4r[j] = hi ? (acc[j + 4] + sw[j + 4]) : (acc[j] + sw[j]);
    }
    float v2[2];
    {
      float sw[4];
#pragma unroll
      for (int j = 0; j < 4; ++j) sw[j] = __shfl_xor(v4r[j], 16, 64);
      const bool hi = (lane & 16) != 0;
      v2[0] = hi ? (v4r[2] + sw[2]) : (v4r[0] + sw[0]);
      v2[1] = hi ? (v4r[3] + sw[3]) : (v4r[1] + sw[1]);
    }
    float w;
    {
      const float s0 = __shfl_xor(v2[0], 8, 64);
      const float s1 = __shfl_xor(v2[1], 8, 64);
      w = ((lane & 8) != 0) ? (v2[1] + s1) : (v2[0] + s0);
    }
    w += __shfl_xor(w, 4, 64);
    w += __shfl_xor(w, 2, 64);
    w += __shfl_xor(w, 1, 64);

    if ((lane & 7) == 0) {
      const int r = lane >> 3;
      const size_t mrow = (size_t)(p * NRR + r) * NKK + k;
      const bool mk = mbyte ? (mb[mrow] != 0) : (mi[mrow] != 0);
      const float l = mk ? -INFINITY : fast_tanh(w) * 10.0f;
      rmax = fmaxf(rmax, l);
      rsum += __expf(l - 10.f);          // exp(-inf) = 0 for masked
    }
  }

  if ((lane & 7) == 0) {
    red[wave][lane >> 3][0] = rmax;
    red[wave][lane >> 3][1] = rsum;
  }
  __syncthreads();
  if (t < NRR) {
    float m = red[0][t][0], s = red[0][t][1];
#pragma unroll
    for (int w = 1; w < 4; ++w) {
      m = fmaxf(m, red[w][t][0]);
      s += red[w][t][1];
    }
    pmax[(size_t)(p * NRR + t) * 32 + kt] = m;
    psum[(size_t)(p * NRR + t) * 32 + kt] = s;
  }

  // ---------- last-block fold: final LSE per row -------------------------
  __syncthreads();                        // partial stores issued
  if (t == 0) {
    __threadfence();                      // publish partials
    lastl = (atomicAdd(&cntl[p], 1) == 31) ? 1 : 0;
  }
  __syncthreads();
  if (lastl) {
    __threadfence();                      // acquire other blocks' partials
    if (t < 256) {
      const int r = t >> 5, k2 = t & 31;
      float m = pmax[(size_t)(p * NRR + r) * 32 + k2];
      float s = psum[(size_t)(p * NRR + r) * 32 + k2];
#pragma unroll
      for (int off = 16; off > 0; off >>= 1) {
        m = fmaxf(m, __shfl_xor(m, off, 64));   // stays within 32-group
        s += __shfl_xor(s, off, 64);
      }
      if (k2 == 0) out_p[p * NRR + r] = m - 10.f - logf(s);
    }
  }
}

// ===========================================================================
// Fallback (ws too small): fused kernel — known-correct.
// ===========================================================================
__global__ __launch_bounds__(256) void k_fused(
    const float* __restrict__ X, const float* __restrict__ Kt,
    const float* __restrict__ Vt, const float* __restrict__ varfeat,
    const void* __restrict__ maskp,
    const float* __restrict__ nn_Q, const float* __restrict__ nn_O,
    const float* __restrict__ nn_A, const float* __restrict__ nn_B,
    const float* __restrict__ nn_W,
    const float* __restrict__ out_h, float* __restrict__ out_p)
{
  const int p = blockIdx.x >> 3;
  const int r = blockIdx.x & 7;
  const int t = threadIdx.x;
  const int wave = t >> 6, lane = t & 63;

  __shared__ float hs[HDIM];
  __shared__ float Qs[NHEAD][HD];
  __shared__ float Sb[NHEAD][NKK];
  __shared__ float xs[HDIM];
  __shared__ float qs[HDIM];
  __shared__ float As2[HDIM][VDIM];
  __shared__ float Ws[HDIM];
  __shared__ float lsb[NKK];
  __shared__ int   mask_any;

  const unsigned char* mb = (const unsigned char*)maskp;
  if (t == 0) mask_any = 0;
  __syncthreads();
  {
    int any = 0;
    for (int j = t; j < 2048; j += 256) any |= mb[2 * j + 1];
    if (any) atomicOr(&mask_any, 1);
  }
  for (int idx = t; idx < VDIM * HDIM; idx += 256)
    As2[idx & 255][idx >> 8] = nn_A[idx];
  Ws[t] = nn_W[t];
  hs[t] = out_h[(size_t)(p * NRR + r) * HDIM + t];
  __syncthreads();
  const bool mbyte = (mask_any != 0);
  const int* mi = (const int*)maskp;
  const size_t mrow = (size_t)(p * NRR + r) * NKK;
  {
    const int a = t >> 5, d = t & 31;
    const float* nq = nn_Q + (size_t)a * HDIM * HD + d;
    float acc = 0.f;
    for (int h = 0; h < HDIM; ++h) acc += hs[h] * nq[(size_t)h * HD];
    Qs[a][d] = acc * 0.17677669529663687f;
  }
  __syncthreads();
  for (int k = t; k < NKK; k += 256) {
    const bool mk = mbyte ? (mb[mrow + k] != 0) : (mi[mrow + k] != 0);
#pragma unroll
    for (int a = 0; a < NHEAD; ++a) {
      const float4* kr4 = reinterpret_cast<const float4*>(
          Kt + (((size_t)a * NPP + p) * NKK + k) * HD);
      float s = 0.f;
#pragma unroll
      for (int d4 = 0; d4 < HD / 4; ++d4) {
        const float4 u = kr4[d4];
        s += Qs[a][4 * d4] * u.x + Qs[a][4 * d4 + 1] * u.y
           + Qs[a][4 * d4 + 2] * u.z + Qs[a][4 * d4 + 3] * u.w;
      }
      Sb[a][k] = mk ? -INFINITY : s;
    }
  }
  __syncthreads();
  for (int aa = 0; aa < 2; ++aa) {
    const int a = wave * 2 + aa;
    float m = -INFINITY;
    for (int k = lane; k < NKK; k += 64) m = fmaxf(m, Sb[a][k]);
#pragma unroll
    for (int off = 32; off > 0; off >>= 1) m = fmaxf(m, __shfl_xor(m, off, 64));
    float ssum = 0.f;
    for (int k = lane; k < NKK; k += 64) {
      const float e = expf(Sb[a][k] - m);
      Sb[a][k] = e; ssum += e;
    }
#pragma unroll
    for (int off = 32; off > 0; off >>= 1) ssum += __shfl_xor(ssum, off, 64);
    const float inv = 1.f / ssum;
    for (int k = lane; k < NKK; k += 64) Sb[a][k] *= inv;
  }
  __syncthreads();
  {
    const int a = t >> 5, d = t & 31;
    const float* vb = Vt + ((size_t)a * NPP + p) * NKK * HD + d;
    float acc = 0.f;
    for (int k = 0; k < NKK; ++k) acc += Sb[a][k] * vb[(size_t)k * HD];
    xs[a * HD + d] = acc;
  }
  __syncthreads();
  {
    float acc = 0.f;
    for (int i = 0; i < HDIM; ++i) acc += xs[i] * nn_O[(size_t)i * HDIM + t];
    qs[t] = acc + nn_B[t];
  }
  __syncthreads();
  for (int k = t; k < NKK; k += 256) {
    float vfv[VDIM];
#pragma unroll
    for (int v = 0; v < VDIM; ++v)
      vfv[v] = varfeat[((size_t)p * VDIM + v) * NKK + k];
    const float4* xp4 = reinterpret_cast<const float4*>(
        X + ((size_t)p * NKK + k) * HDIM);
    float acc = 0.f;
    for (int h4 = 0; h4 < HDIM / 4; ++h4) {
      const float4 ux = xp4[h4];
      const float xv[4] = {ux.x, ux.y, ux.z, ux.w};
#pragma unroll
      for (int j = 0; j < 4; ++j) {
        const int h = 4 * h4 + j;
        float base = xv[j] + qs[h];
        const float4 a0 = *reinterpret_cast<const float4*>(&As2[h][0]);
        const float4 a1 = *reinterpret_cast<const float4*>(&As2[h][4]);
        base += vfv[0] * a0.x + vfv[1] * a0.y + vfv[2] * a0.z + vfv[3] * a0.w
              + vfv[4] * a1.x + vfv[5] * a1.y + vfv[6] * a1.z + vfv[7] * a1.w;
        acc += tanhf(base) * Ws[h];
      }
    }
    lsb[k] = acc;
  }
  __syncthreads();
  for (int k = t; k < NKK; k += 256) {
    const bool mk = mbyte ? (mb[mrow + k] != 0) : (mi[mrow + k] != 0);
    lsb[k] = mk ? -INFINITY : tanhf(lsb[k]) * 10.0f;
  }
  __syncthreads();
  if (wave == 0) {
    float m = -INFINITY;
    for (int k = lane; k < NKK; k += 64) m = fmaxf(m, lsb[k]);
#pragma unroll
    for (int off = 32; off > 0; off >>= 1) m = fmaxf(m, __shfl_xor(m, off, 64));
    float s = 0.f;
    for (int k = lane; k < NKK; k += 64) s += expf(lsb[k] - m);
#pragma unroll
    for (int off = 32; off > 0; off >>= 1) s += __shfl_xor(s, off, 64);
    if (lane == 0) out_p[p * NRR + r] = -logf(s);
  }
}

// ===========================================================================
extern "C" void kernel_launch(void* const* d_in, const int* in_sizes, int n_in,
                              void* d_out, int out_size, void* d_ws, size_t ws_size,
                              hipStream_t stream)
{
  const float* X       = (const float*)d_in[0];
  const float* Kt      = (const float*)d_in[1];
  const float* Vt      = (const float*)d_in[2];
  const float* query   = (const float*)d_in[3];
  const float* state1  = (const float*)d_in[4];
  const float* state2  = (const float*)d_in[5];
  const float* varfeat = (const float*)d_in[6];
  const void*  maskp   = d_in[7];
  const float* nn_Q    = (const float*)d_in[8];
  const float* nn_O    = (const float*)d_in[9];
  const float* nn_A    = (const float*)d_in[10];
  const float* nn_B    = (const float*)d_in[11];
  const float* nn_W    = (const float*)d_in[12];
  const float* W_ih    = (const float*)d_in[13];
  const float* W_hh    = (const float*)d_in[14];
  const float* b_ih    = (const float*)d_in[15];
  const float* b_hh    = (const float*)d_in[16];

  float* out   = (float*)d_out;
  float* out_h = out;
  float* out_c = out + (size_t)BTOT * HDIM;
  float* out_p = out + (size_t)2 * BTOT * HDIM;

  // ws layout: flag(4B) | cnta(64 int @ +256) | cntl(64 int @ +512) |
  //            pad to 1024 | qm8 (4MB) | qbg (512KB) | pmax | psum
  const size_t hdr_bytes  = 1024;
  const size_t qm8_bytes  = (size_t)NHEAD * BTOT * HDIM * 4;   // 4 MB
  const size_t qbg_bytes  = (size_t)BTOT * HDIM * 4;           // 512 KB
  const size_t part_bytes = (size_t)BTOT * 32 * 4;             // 64 KB each
  const size_t need = hdr_bytes + qm8_bytes + qbg_bytes + 2 * part_bytes;

  if (ws_size >= need) {
    int*   flagp = (int*)d_ws;
    int*   cnts  = (int*)((char*)d_ws + 256);     // cnta(64) + cntl(64)
    int*   cnta  = cnts;
    int*   cntl  = (int*)((char*)d_ws + 512);
    float* qmw  = (float*)((char*)d_ws + hdr_bytes);
    float* qbg  = (float*)((char*)d_ws + hdr_bytes + qm8_bytes);
    float* pmax = (float*)((char*)d_ws + hdr_bytes + qm8_bytes + qbg_bytes);
    float* psum = (float*)((char*)d_ws + hdr_bytes + qm8_bytes + qbg_bytes
                           + part_bytes);

    hipLaunchKernelGGL(k_lstm3, dim3(32, 16), dim3(256), 0, stream,
                       query, state1, state2, W_ih, W_hh, b_ih, b_hh,
                       (const unsigned char*)maskp, flagp, cnts,
                       out_h, out_c);
    hipLaunchKernelGGL(k_attn11, dim3(NPP * NHEAD), dim3(512), 0, stream,
                       Kt, Vt, nn_Q, nn_O, nn_B, maskp, flagp, cnta,
                       out_h, qmw, qbg);
    hipLaunchKernelGGL(k_logits8, dim3(NPP * 32), dim3(256), 0, stream,
                       X, varfeat, nn_A, nn_W, qbg, flagp, maskp, cntl,
                       pmax, psum, out_p);
  } else {
    hipLaunchKernelGGL(k_lstm3, dim3(32, 16), dim3(256), 0, stream,
                       query, state1, state2, W_ih, W_hh, b_ih, b_hh,
                       (const unsigned char*)maskp, nullptr, nullptr,
                       out_h, out_c);
    hipLaunchKernelGGL(k_fused, dim3(NPP * NRR), dim3(256), 0, stream,
                       X, Kt, Vt, varfeat, maskp,
                       nn_Q, nn_O, nn_A, nn_B, nn_W,
                       out_h, out_p);
  }
}

// Round 6
// 230.758 us; speedup vs baseline: 1.5991x; 1.5991x over previous
//
#include <hip/hip_runtime.h>

// Problem constants (from reference) — ALL TENSORS ARE FLOAT32.
#define NPP   64
#define NRR   8
#define NKK   500
#define HDIM  256
#define NHEAD 8
#define VDIM  8
#define HD    32
#define BTOT  512   // NPP*NRR

// ---- fast transcendentals (hardware v_exp_f32 / v_rcp_f32) ----
__device__ __forceinline__ float fast_tanh(float x) {
  const float e = __expf(2.f * x);
  return 1.f - 2.f * __builtin_amdgcn_rcpf(e + 1.f);
}
__device__ __forceinline__ float fast_sig(float x) {
  return __builtin_amdgcn_rcpf(1.f + __expf(-x));
}

// keep-live pins: force loads to issue early / complete here (rule #17)
#define PIN1(x)  asm volatile("" :: "v"(x))
#define PIN4(v)  asm volatile("" :: "v"((v).x), "v"((v).y), "v"((v).z), "v"((v).w))

// ===========================================================================
// Kernel 1: LSTM cell GEMM (round-4 config).  Tile 32 gate-rows x 64 batch,
// 128 thr, 4x4/thread via ds_read_b128; async reg-staged global loads.
// Grid 32 x 8.  Block (0,0) probes mask dtype into ws flag.
// ===========================================================================
__global__ __launch_bounds__(128) void k_lstm5(
    const float* __restrict__ query, const float* __restrict__ state1,
    const float* __restrict__ state2,
    const float* __restrict__ W_ih, const float* __restrict__ W_hh,
    const float* __restrict__ b_ih, const float* __restrict__ b_hh,
    const unsigned char* __restrict__ maskb, int* __restrict__ flagp,
    float* __restrict__ out_h, float* __restrict__ out_c)
{
  __shared__ float Wt[32][36];   // [k][gate-row]   4.6 KB
  __shared__ float At[32][68];   // [k][batch-col]  8.7 KB
  __shared__ float gt[32][68];   // gate exchange   8.7 KB

  const int t  = threadIdx.x;    // 128
  const int hb = blockIdx.x;     // 32 tiles of 8 h (x4 gate parts)
  const int bb = blockIdx.y;     // 8 batch tiles of 64

  if (flagp != nullptr && hb == 0 && bb == 0) {
    __shared__ int f;
    if (t == 0) f = 0;
    __syncthreads();
    int any = 0;
    for (int j = t; j < 2048; j += 128) any |= maskb[2 * j + 1];
    if (any) atomicOr(&f, 1);
    __syncthreads();
    if (t == 0) *flagp = f;
  }

  const int tr = t >> 4;                 // 0..7   -> gate-rows tr*4..+3
  const int tc = t & 15;                 // 0..15  -> batch    tc*4..+3

  const int grow = t >> 2;               // 0..31 local gate-row
  const int kseg = t & 3;                // k-quarter (8 floats)
  const int wgrow = (grow >> 3) * HDIM + hb * 8 + (grow & 7);
  const int agrow0 = bb * 64 + grow;     // batch rows grow, grow+32
  const int agrow1 = agrow0 + 32;

  float4 wr0, wr1, ar0, ar1, ar2, ar3;

#define LSTM_ISSUE(K0)                                                        \
  {                                                                           \
    const int k0_ = (K0);                                                     \
    const float* wsrc = (k0_ < 256)                                           \
        ? (W_ih + (size_t)wgrow * HDIM + k0_)                                 \
        : (W_hh + (size_t)wgrow * HDIM + (k0_ - 256));                        \
    wr0 = *reinterpret_cast<const float4*>(wsrc + kseg * 8);                  \
    wr1 = *reinterpret_cast<const float4*>(wsrc + kseg * 8 + 4);              \
    const float* asrc0 = (k0_ < 256)                                          \
        ? (query  + (size_t)agrow0 * HDIM + k0_)                              \
        : (state1 + (size_t)agrow0 * HDIM + (k0_ - 256));                     \
    ar0 = *reinterpret_cast<const float4*>(asrc0 + kseg * 8);                 \
    ar1 = *reinterpret_cast<const float4*>(asrc0 + kseg * 8 + 4);             \
    const float* asrc1 = (k0_ < 256)                                          \
        ? (query  + (size_t)agrow1 * HDIM + k0_)                              \
        : (state1 + (size_t)agrow1 * HDIM + (k0_ - 256));                     \
    ar2 = *reinterpret_cast<const float4*>(asrc1 + kseg * 8);                 \
    ar3 = *reinterpret_cast<const float4*>(asrc1 + kseg * 8 + 4);             \
  }

#define LSTM_WRITE()                                                          \
  {                                                                           \
    const float w0[4] = {wr0.x, wr0.y, wr0.z, wr0.w};                         \
    const float w1[4] = {wr1.x, wr1.y, wr1.z, wr1.w};                         \
    const float a0[4] = {ar0.x, ar0.y, ar0.z, ar0.w};                         \
    const float a1[4] = {ar1.x, ar1.y, ar1.z, ar1.w};                         \
    const float a2[4] = {ar2.x, ar2.y, ar2.z, ar2.w};                         \
    const float a3[4] = {ar3.x, ar3.y, ar3.z, ar3.w};                         \
    _Pragma("unroll")                                                         \
    for (int i = 0; i < 4; ++i) {                                             \
      Wt[kseg * 8 + i][grow]     = w0[i];                                     \
      Wt[kseg * 8 + 4 + i][grow] = w1[i];                                     \
      At[kseg * 8 + i][grow]     = a0[i];                                     \
      At[kseg * 8 + 4 + i][grow] = a1[i];                                     \
      At[kseg * 8 + i][grow + 32]     = a2[i];                                \
      At[kseg * 8 + 4 + i][grow + 32] = a3[i];                                \
    }                                                                         \
  }

  float acc[4][4];
#pragma unroll
  for (int i = 0; i < 4; ++i)
#pragma unroll
    for (int j = 0; j < 4; ++j) acc[i][j] = 0.f;

  LSTM_ISSUE(0);
  LSTM_WRITE();
  __syncthreads();

  for (int k0 = 0; k0 < 512; k0 += 32) {
    const bool more = (k0 + 32) < 512;
    if (more) LSTM_ISSUE(k0 + 32);       // in flight during compute

#pragma unroll 8
    for (int kk = 0; kk < 32; ++kk) {
      const float4 wv = *reinterpret_cast<const float4*>(&Wt[kk][tr * 4]);
      const float4 av = *reinterpret_cast<const float4*>(&At[kk][tc * 4]);
      const float w[4] = {wv.x, wv.y, wv.z, wv.w};
      const float a[4] = {av.x, av.y, av.z, av.w};
#pragma unroll
      for (int i = 0; i < 4; ++i)
#pragma unroll
        for (int j = 0; j < 4; ++j) acc[i][j] += w[i] * a[j];
    }
    __syncthreads();
    if (more) {
      LSTM_WRITE();
      __syncthreads();
    }
  }

#pragma unroll
  for (int i = 0; i < 4; ++i) {
    float4 v;
    v.x = acc[i][0]; v.y = acc[i][1]; v.z = acc[i][2]; v.w = acc[i][3];
    *reinterpret_cast<float4*>(&gt[tr * 4 + i][tc * 4]) = v;
  }
  __syncthreads();

#pragma unroll
  for (int it = 0; it < 4; ++it) {
    const int cell = t + 128 * it;       // 512 cells = 8 h x 64 b
    const int h = cell & 7, b = cell >> 3;
    const int gh = hb * 8 + h;
    const int gb = bb * 64 + b;
    const float bi = b_ih[0 * HDIM + gh] + b_hh[0 * HDIM + gh];
    const float bf = b_ih[1 * HDIM + gh] + b_hh[1 * HDIM + gh];
    const float bg = b_ih[2 * HDIM + gh] + b_hh[2 * HDIM + gh];
    const float bo = b_ih[3 * HDIM + gh] + b_hh[3 * HDIM + gh];
    const float iv = fast_sig (gt[ 0 + h][b] + bi);
    const float fv = fast_sig (gt[ 8 + h][b] + bf);
    const float gv = fast_tanh(gt[16 + h][b] + bg);
    const float ov = fast_sig (gt[24 + h][b] + bo);
    const size_t off = (size_t)gb * HDIM + gh;
    const float c = fv * state2[off] + iv * gv;
    out_c[off] = c;
    out_h[off] = ov * fast_tanh(c);
  }
}

// ===========================================================================
// Kernel 2: attention per (p, head), 512 threads, VGPR cap 128 (4 waves/EU).
// SINGLE CHANGE vs round-4 attn10: entry-burst loads (h, K, V, mask) are
// PINNED so the compiler cannot sink them past the first barrier; nn_O is
// prefetched into registers 3 phases before its use.  No fences, no folds.
// ===========================================================================
__global__ __launch_bounds__(512, 4) void k_attn12(
    const float* __restrict__ Kt, const float* __restrict__ Vt,
    const float* __restrict__ nn_Q, const float* __restrict__ nn_O,
    const void* __restrict__ maskp, const int* __restrict__ flagp,
    const float* __restrict__ out_h, float* __restrict__ qm_slabs)
{
  const int p = blockIdx.x >> 3;
  const int a = blockIdx.x & 7;
  const int t = threadIdx.x;
  const int wave = t >> 6, lane = t & 63;

  __shared__ float hs[NRR][HDIM];       // 8 KB
  __shared__ float Qs[NRR][36];         // 1.2 KB
  __shared__ float Sb[NRR][512];        // 16 KB (cols 500..511 = -inf pad)
  __shared__ float pb[8][NRR][HD];      // 8 KB per-wave PV partials
  __shared__ float xs[NRR][36];         // 1.2 KB

  // ---------- entry burst: h, K, V, mask all in flight -------------------
  const float4 hv = reinterpret_cast<const float4*>(
      out_h + (size_t)p * NRR * HDIM)[t];

  const int flag = *flagp;

  const int kc = (t < NKK) ? t : (NKK - 1);
  const float4* kp4 = reinterpret_cast<const float4*>(
      Kt + (((size_t)a * NPP + p) * NKK + kc) * HD);
  float4 kreg[8];
#pragma unroll
  for (int j = 0; j < 8; ++j) kreg[j] = kp4[j];

  const int kg = t >> 3;                // 0..63  k-group
  const int d4p = t & 7;                // f4 dim slot
  float4 v4[8];
  {
    const float* vbase = Vt + ((size_t)a * NPP + p) * NKK * HD + d4p * 4;
#pragma unroll
    for (int j = 0; j < 8; ++j) {
      const int k = kg + 64 * j;
      v4[j] = (k < NKK)
          ? *reinterpret_cast<const float4*>(vbase + (size_t)k * HD)
          : make_float4(0.f, 0.f, 0.f, 0.f);
    }
  }

  float maskv[NRR];
  {
    const unsigned char* mb = (const unsigned char*)maskp;
    const int* mi = (const int*)maskp;
#pragma unroll
    for (int r = 0; r < NRR; ++r) {
      const size_t mo = (size_t)(p * NRR + r) * NKK + kc;
      const bool mk = flag ? (mb[mo] != 0) : (mi[mo] != 0);
      maskv[r] = mk ? -INFINITY : 0.f;
    }
  }

  reinterpret_cast<float4*>(&hs[0][0])[t] = hv;

  // pin: loads must be issued by here; the single wait coincides with the
  // hs barrier, so all later phases run out of registers with no vm waits.
#pragma unroll
  for (int j = 0; j < 8; ++j) { PIN4(kreg[j]); PIN4(v4[j]); }
#pragma unroll
  for (int r = 0; r < NRR; ++r) PIN1(maskv[r]);
  __syncthreads();

  // ---------- Q-proj: wave r; lane = (d4, ks); ks stride 4 ---------------
  {
    const int r = wave;
    const int d4 = lane >> 3, ks = lane & 7;
    float qx = 0.f, qy = 0.f, qz = 0.f, qw = 0.f;
#pragma unroll
    for (int i = 0; i < 8; ++i) {
      const int hb = 32 * i + ks * 4;
      const float4 hv4 = *reinterpret_cast<const float4*>(&hs[r][hb]);
      const float hh[4] = {hv4.x, hv4.y, hv4.z, hv4.w};
      const float* nqb = nn_Q + ((size_t)a * HDIM + hb) * HD + d4 * 4;
#pragma unroll
      for (int jj = 0; jj < 4; ++jj) {
        const float4 wv = *reinterpret_cast<const float4*>(nqb + (size_t)jj * HD);
        qx += hh[jj] * wv.x; qy += hh[jj] * wv.y;
        qz += hh[jj] * wv.z; qw += hh[jj] * wv.w;
      }
    }
#pragma unroll
    for (int off = 1; off < 8; off <<= 1) {
      qx += __shfl_xor(qx, off, 64);
      qy += __shfl_xor(qy, off, 64);
      qz += __shfl_xor(qz, off, 64);
      qw += __shfl_xor(qw, off, 64);
    }
    if (ks == 0) {
      const float sc = 0.17677669529663687f;   // 1/sqrt(32)
      Qs[r][d4 * 4 + 0] = qx * sc; Qs[r][d4 * 4 + 1] = qy * sc;
      Qs[r][d4 * 4 + 2] = qz * sc; Qs[r][d4 * 4 + 3] = qw * sc;
    }
  }
  __syncthreads();

  // ---------- scores from pinned kreg ------------------------------------
#pragma unroll
  for (int r = 0; r < NRR; ++r) {
    float s = 0.f;
#pragma unroll
    for (int j = 0; j < 8; ++j) {
      const float4 q = *reinterpret_cast<const float4*>(&Qs[r][j * 4]);
      const float4 k4 = kreg[j];
      s += q.x * k4.x + q.y * k4.y + q.z * k4.z + q.w * k4.w;
    }
    Sb[r][t] = (t < NKK) ? (s + maskv[r]) : -INFINITY;
  }

  // ---------- nn_O prefetch: 3 phases ahead of its use -------------------
  const int j8 = t & 255;
  float orr[32];
  {
    const float* ob = nn_O + (size_t)(a * HD) * HDIM + j8;
#pragma unroll
    for (int d = 0; d < 32; ++d) orr[d] = ob[(size_t)d * HDIM];
  }
  __syncthreads();

  // ---------- softmax: wave w -> rollout w -------------------------------
  {
    const int r = wave;
    float lv[8], m = -INFINITY;
#pragma unroll
    for (int i = 0; i < 8; ++i) {
      lv[i] = Sb[r][lane + 64 * i];
      m = fmaxf(m, lv[i]);
    }
#pragma unroll
    for (int off = 32; off > 0; off >>= 1) m = fmaxf(m, __shfl_xor(m, off, 64));
    float ssum = 0.f;
#pragma unroll
    for (int i = 0; i < 8; ++i) {
      lv[i] = __expf(lv[i] - m);
      ssum += lv[i];
    }
#pragma unroll
    for (int off = 32; off > 0; off >>= 1) ssum += __shfl_xor(ssum, off, 64);
    const float inv = 1.f / ssum;
#pragma unroll
    for (int i = 0; i < 8; ++i) Sb[r][lane + 64 * i] = lv[i] * inv;
  }
  __syncthreads();

  // ---------- PV: pinned V regs x Sb broadcasts; shfl-reduce over kg -----
  {
    float4 acc4[NRR];
#pragma unroll
    for (int r = 0; r < NRR; ++r) acc4[r] = make_float4(0.f, 0.f, 0.f, 0.f);
#pragma unroll
    for (int j = 0; j < 8; ++j) {
      const float4 v = v4[j];
#pragma unroll
      for (int r = 0; r < NRR; ++r) {
        const float s = Sb[r][kg + 64 * j];   // pad rows are exact 0
        acc4[r].x += s * v.x; acc4[r].y += s * v.y;
        acc4[r].z += s * v.z; acc4[r].w += s * v.w;
      }
    }
#pragma unroll
    for (int off = 8; off < 64; off <<= 1) {
#pragma unroll
      for (int r = 0; r < NRR; ++r) {
        acc4[r].x += __shfl_xor(acc4[r].x, off, 64);
        acc4[r].y += __shfl_xor(acc4[r].y, off, 64);
        acc4[r].z += __shfl_xor(acc4[r].z, off, 64);
        acc4[r].w += __shfl_xor(acc4[r].w, off, 64);
      }
    }
    if (lane < 8) {
#pragma unroll
      for (int r = 0; r < NRR; ++r)
        *reinterpret_cast<float4*>(&pb[wave][r][lane * 4]) = acc4[r];
    }
  }
  __syncthreads();

  if (t < 256) {
    const int r = t >> 5, d = t & 31;
    float s = 0.f;
#pragma unroll
    for (int w = 0; w < 8; ++w) s += pb[w][r][d];
    xs[r][d] = s;
  }
  __syncthreads();

  // ---------- O-proj from register-resident nn_O -> per-head slab --------
  {
    const int rr = t >> 8;                // row-group {0..3} or {4..7}
    float a0 = 0.f, a1 = 0.f, a2 = 0.f, a3 = 0.f;
#pragma unroll
    for (int d4 = 0; d4 < 8; ++d4) {
      const float4 x0 = *reinterpret_cast<const float4*>(&xs[rr * 4 + 0][d4 * 4]);
      const float4 x1 = *reinterpret_cast<const float4*>(&xs[rr * 4 + 1][d4 * 4]);
      const float4 x2 = *reinterpret_cast<const float4*>(&xs[rr * 4 + 2][d4 * 4]);
      const float4 x3 = *reinterpret_cast<const float4*>(&xs[rr * 4 + 3][d4 * 4]);
      const float c0[4] = {x0.x, x0.y, x0.z, x0.w};
      const float c1[4] = {x1.x, x1.y, x1.z, x1.w};
      const float c2[4] = {x2.x, x2.y, x2.z, x2.w};
      const float c3[4] = {x3.x, x3.y, x3.z, x3.w};
#pragma unroll
      for (int dd = 0; dd < 4; ++dd) {
        const float w = orr[d4 * 4 + dd];
        a0 += c0[dd] * w; a1 += c1[dd] * w;
        a2 += c2[dd] * w; a3 += c3[dd] * w;
      }
    }
    float* slab = qm_slabs + (size_t)a * BTOT * HDIM;
    slab[(size_t)(p * NRR + rr * 4 + 0) * HDIM + j8] = a0;
    slab[(size_t)(p * NRR + rr * 4 + 1) * HDIM + j8] = a1;
    slab[(size_t)(p * NRR + rr * 4 + 2) * HDIM + j8] = a2;
    slab[(size_t)(p * NRR + rr * 4 + 3) * HDIM + j8] = a3;
  }
}

// ===========================================================================
// Kernel 3: qbg[512][256] = sum_a qm_slab[a] + nn_B.  Grid 128 x 256 thr.
// ===========================================================================
__global__ __launch_bounds__(256) void k_qsum(
    const float* __restrict__ qm_slabs, const float* __restrict__ nn_B,
    float* __restrict__ qbg)
{
  const int idx = blockIdx.x * 256 + threadIdx.x;   // 32768 f4 slots
  const int row = idx >> 6, h4 = idx & 63;
  float4 acc = *reinterpret_cast<const float4*>(nn_B + h4 * 4);
#pragma unroll
  for (int a = 0; a < NHEAD; ++a) {
    const float4 q = *reinterpret_cast<const float4*>(
        qm_slabs + (size_t)a * BTOT * HDIM + (size_t)row * HDIM + h4 * 4);
    acc.x += q.x; acc.y += q.y; acc.z += q.z; acc.w += q.w;
  }
  *reinterpret_cast<float4*>(qbg + (size_t)row * HDIM + h4 * 4) = acc;
}

// ===========================================================================
// Kernel 4: additive logits + per-(row, kt) softmax partials (round-4 ver,
// no folds).  Grid 64 x 32.  Wave owns 4 k; lane owns 4 h.
// ===========================================================================
__global__ __launch_bounds__(256) void k_logits7(
    const float* __restrict__ X, const float* __restrict__ varfeat,
    const float* __restrict__ nn_A, const float* __restrict__ nn_W,
    const float* __restrict__ qbg,
    const int* __restrict__ flagp, const void* __restrict__ maskp,
    float* __restrict__ pmax, float* __restrict__ psum)
{
  const int p  = blockIdx.x >> 5;
  const int kt = blockIdx.x & 31;
  const int t = threadIdx.x;
  const int wave = t >> 6, lane = t & 63;
  const int h0 = lane * 4;

  __shared__ float red[4][NRR][2];      // per-wave (max, sum) partials

  const unsigned char* mb = (const unsigned char*)maskp;
  const int* mi = (const int*)maskp;
  const int flag = *flagp;
  const bool mbyte = (flag != 0);

  const float4 w4 = *reinterpret_cast<const float4*>(nn_W + h0);
  float4 a4r[VDIM];
#pragma unroll
  for (int v = 0; v < VDIM; ++v)
    a4r[v] = *reinterpret_cast<const float4*>(nn_A + (size_t)v * HDIM + h0);
  float4 q4r[NRR];
#pragma unroll
  for (int r = 0; r < NRR; ++r)
    q4r[r] = *reinterpret_cast<const float4*>(
        qbg + (size_t)(p * NRR + r) * HDIM + h0);

  float rmax = -INFINITY, rsum = 0.f;    // valid at lanes with (lane&7)==0

  for (int kk = 0; kk < 4; ++kk) {
    const int k = kt * 16 + wave * 4 + kk;
    if (k >= NKK) break;   // wave-uniform

    const float4 x4 = *reinterpret_cast<const float4*>(
        X + ((size_t)p * NKK + k) * HDIM + h0);
    float base0 = x4.x, base1 = x4.y, base2 = x4.z, base3 = x4.w;
#pragma unroll
    for (int v = 0; v < VDIM; ++v) {
      const float vv = varfeat[((size_t)p * VDIM + v) * NKK + k];
      base0 += vv * a4r[v].x; base1 += vv * a4r[v].y;
      base2 += vv * a4r[v].z; base3 += vv * a4r[v].w;
    }

    float acc[NRR];
#pragma unroll
    for (int r = 0; r < NRR; ++r) {
      acc[r] = fast_tanh(base0 + q4r[r].x) * w4.x
             + fast_tanh(base1 + q4r[r].y) * w4.y
             + fast_tanh(base2 + q4r[r].z) * w4.z
             + fast_tanh(base3 + q4r[r].w) * w4.w;
    }

    // multi-value wave reduction: 8 sums across 64 lanes
    float v4r[4];
    {
      float sw[8];
#pragma unroll
      for (int j = 0; j < 8; ++j) sw[j] = __shfl_xor(acc[j], 32, 64);
      const bool hi = (lane & 32) != 0;
#pragma unroll
      for (int j = 0; j < 4; ++j)
        v4r[j] = hi ? (acc[j + 4] + sw[j + 4]) : (acc[j] + sw[j]);
    }
    float v2[2];
    {
      float sw[4];
#pragma unroll
      for (int j = 0; j < 4; ++j) sw[j] = __shfl_xor(v4r[j], 16, 64);
      const bool hi = (lane & 16) != 0;
      v2[0] = hi ? (v4r[2] + sw[2]) : (v4r[0] + sw[0]);
      v2[1] = hi ? (v4r[3] + sw[3]) : (v4r[1] + sw[1]);
    }
    float w;
    {
      const float s0 = __shfl_xor(v2[0], 8, 64);
      const float s1 = __shfl_xor(v2[1], 8, 64);
      w = ((lane & 8) != 0) ? (v2[1] + s1) : (v2[0] + s0);
    }
    w += __shfl_xor(w, 4, 64);
    w += __shfl_xor(w, 2, 64);
    w += __shfl_xor(w, 1, 64);

    if ((lane & 7) == 0) {
      const int r = lane >> 3;
      const size_t mrow = (size_t)(p * NRR + r) * NKK + k;
      const bool mk = mbyte ? (mb[mrow] != 0) : (mi[mrow] != 0);
      const float l = mk ? -INFINITY : fast_tanh(w) * 10.0f;
      rmax = fmaxf(rmax, l);
      rsum += __expf(l - 10.f);          // exp(-inf) = 0 for masked
    }
  }

  if ((lane & 7) == 0) {
    red[wave][lane >> 3][0] = rmax;
    red[wave][lane >> 3][1] = rsum;
  }
  __syncthreads();
  if (t < NRR) {
    float m = red[0][t][0], s = red[0][t][1];
#pragma unroll
    for (int w = 1; w < 4; ++w) {
      m = fmaxf(m, red[w][t][0]);
      s += red[w][t][1];
    }
    pmax[(size_t)(p * NRR + t) * 32 + kt] = m;
    psum[(size_t)(p * NRR + t) * 32 + kt] = s;
  }
}

// ===========================================================================
// Kernel 5: choose.  One wave per batch row; reduce the 32 kt-partials.
// chosen_p = m - LSE = m - 10 - log(sum exp(l-10)).
// ===========================================================================
__global__ __launch_bounds__(64) void k_choose2(
    const float* __restrict__ pmax, const float* __restrict__ psum,
    float* __restrict__ out_p)
{
  const int b = blockIdx.x;
  const int lane = threadIdx.x;
  float m = (lane < 32) ? pmax[(size_t)b * 32 + lane] : -INFINITY;
  float s = (lane < 32) ? psum[(size_t)b * 32 + lane] : 0.f;
#pragma unroll
  for (int off = 16; off > 0; off >>= 1) {
    m = fmaxf(m, __shfl_xor(m, off, 64));
    s += __shfl_xor(s, off, 64);
  }
  if (lane == 0) out_p[b] = m - 10.f - logf(s);
}

// ===========================================================================
// Fallback (ws too small): fused kernel — known-correct.
// ===========================================================================
__global__ __launch_bounds__(256) void k_fused(
    const float* __restrict__ X, const float* __restrict__ Kt,
    const float* __restrict__ Vt, const float* __restrict__ varfeat,
    const void* __restrict__ maskp,
    const float* __restrict__ nn_Q, const float* __restrict__ nn_O,
    const float* __restrict__ nn_A, const float* __restrict__ nn_B,
    const float* __restrict__ nn_W,
    const float* __restrict__ out_h, float* __restrict__ out_p)
{
  const int p = blockIdx.x >> 3;
  const int r = blockIdx.x & 7;
  const int t = threadIdx.x;
  const int wave = t >> 6, lane = t & 63;

  __shared__ float hs[HDIM];
  __shared__ float Qs[NHEAD][HD];
  __shared__ float Sb[NHEAD][NKK];
  __shared__ float xs[HDIM];
  __shared__ float qs[HDIM];
  __shared__ float As2[HDIM][VDIM];
  __shared__ float Ws[HDIM];
  __shared__ float lsb[NKK];
  __shared__ int   mask_any;

  const unsigned char* mb = (const unsigned char*)maskp;
  if (t == 0) mask_any = 0;
  __syncthreads();
  {
    int any = 0;
    for (int j = t; j < 2048; j += 256) any |= mb[2 * j + 1];
    if (any) atomicOr(&mask_any, 1);
  }
  for (int idx = t; idx < VDIM * HDIM; idx += 256)
    As2[idx & 255][idx >> 8] = nn_A[idx];
  Ws[t] = nn_W[t];
  hs[t] = out_h[(size_t)(p * NRR + r) * HDIM + t];
  __syncthreads();
  const bool mbyte = (mask_any != 0);
  const int* mi = (const int*)maskp;
  const size_t mrow = (size_t)(p * NRR + r) * NKK;
  {
    const int a = t >> 5, d = t & 31;
    const float* nq = nn_Q + (size_t)a * HDIM * HD + d;
    float acc = 0.f;
    for (int h = 0; h < HDIM; ++h) acc += hs[h] * nq[(size_t)h * HD];
    Qs[a][d] = acc * 0.17677669529663687f;
  }
  __syncthreads();
  for (int k = t; k < NKK; k += 256) {
    const bool mk = mbyte ? (mb[mrow + k] != 0) : (mi[mrow + k] != 0);
#pragma unroll
    for (int a = 0; a < NHEAD; ++a) {
      const float4* kr4 = reinterpret_cast<const float4*>(
          Kt + (((size_t)a * NPP + p) * NKK + k) * HD);
      float s = 0.f;
#pragma unroll
      for (int d4 = 0; d4 < HD / 4; ++d4) {
        const float4 u = kr4[d4];
        s += Qs[a][4 * d4] * u.x + Qs[a][4 * d4 + 1] * u.y
           + Qs[a][4 * d4 + 2] * u.z + Qs[a][4 * d4 + 3] * u.w;
      }
      Sb[a][k] = mk ? -INFINITY : s;
    }
  }
  __syncthreads();
  for (int aa = 0; aa < 2; ++aa) {
    const int a = wave * 2 + aa;
    float m = -INFINITY;
    for (int k = lane; k < NKK; k += 64) m = fmaxf(m, Sb[a][k]);
#pragma unroll
    for (int off = 32; off > 0; off >>= 1) m = fmaxf(m, __shfl_xor(m, off, 64));
    float ssum = 0.f;
    for (int k = lane; k < NKK; k += 64) {
      const float e = expf(Sb[a][k] - m);
      Sb[a][k] = e; ssum += e;
    }
#pragma unroll
    for (int off = 32; off > 0; off >>= 1) ssum += __shfl_xor(ssum, off, 64);
    const float inv = 1.f / ssum;
    for (int k = lane; k < NKK; k += 64) Sb[a][k] *= inv;
  }
  __syncthreads();
  {
    const int a = t >> 5, d = t & 31;
    const float* vb = Vt + ((size_t)a * NPP + p) * NKK * HD + d;
    float acc = 0.f;
    for (int k = 0; k < NKK; ++k) acc += Sb[a][k] * vb[(size_t)k * HD];
    xs[a * HD + d] = acc;
  }
  __syncthreads();
  {
    float acc = 0.f;
    for (int i = 0; i < HDIM; ++i) acc += xs[i] * nn_O[(size_t)i * HDIM + t];
    qs[t] = acc + nn_B[t];
  }
  __syncthreads();
  for (int k = t; k < NKK; k += 256) {
    float vfv[VDIM];
#pragma unroll
    for (int v = 0; v < VDIM; ++v)
      vfv[v] = varfeat[((size_t)p * VDIM + v) * NKK + k];
    const float4* xp4 = reinterpret_cast<const float4*>(
        X + ((size_t)p * NKK + k) * HDIM);
    float acc = 0.f;
    for (int h4 = 0; h4 < HDIM / 4; ++h4) {
      const float4 ux = xp4[h4];
      const float xv[4] = {ux.x, ux.y, ux.z, ux.w};
#pragma unroll
      for (int j = 0; j < 4; ++j) {
        const int h = 4 * h4 + j;
        float base = xv[j] + qs[h];
        const float4 a0 = *reinterpret_cast<const float4*>(&As2[h][0]);
        const float4 a1 = *reinterpret_cast<const float4*>(&As2[h][4]);
        base += vfv[0] * a0.x + vfv[1] * a0.y + vfv[2] * a0.z + vfv[3] * a0.w
              + vfv[4] * a1.x + vfv[5] * a1.y + vfv[6] * a1.z + vfv[7] * a1.w;
        acc += tanhf(base) * Ws[h];
      }
    }
    lsb[k] = acc;
  }
  __syncthreads();
  for (int k = t; k < NKK; k += 256) {
    const bool mk = mbyte ? (mb[mrow + k] != 0) : (mi[mrow + k] != 0);
    lsb[k] = mk ? -INFINITY : tanhf(lsb[k]) * 10.0f;
  }
  __syncthreads();
  if (wave == 0) {
    float m = -INFINITY;
    for (int k = lane; k < NKK; k += 64) m = fmaxf(m, lsb[k]);
#pragma unroll
    for (int off = 32; off > 0; off >>= 1) m = fmaxf(m, __shfl_xor(m, off, 64));
    float s = 0.f;
    for (int k = lane; k < NKK; k += 64) s += expf(lsb[k] - m);
#pragma unroll
    for (int off = 32; off > 0; off >>= 1) s += __shfl_xor(s, off, 64);
    if (lane == 0) out_p[p * NRR + r] = -logf(s);
  }
}

// ===========================================================================
extern "C" void kernel_launch(void* const* d_in, const int* in_sizes, int n_in,
                              void* d_out, int out_size, void* d_ws, size_t ws_size,
                              hipStream_t stream)
{
  const float* X       = (const float*)d_in[0];
  const float* Kt      = (const float*)d_in[1];
  const float* Vt      = (const float*)d_in[2];
  const float* query   = (const float*)d_in[3];
  const float* state1  = (const float*)d_in[4];
  const float* state2  = (const float*)d_in[5];
  const float* varfeat = (const float*)d_in[6];
  const void*  maskp   = d_in[7];
  const float* nn_Q    = (const float*)d_in[8];
  const float* nn_O    = (const float*)d_in[9];
  const float* nn_A    = (const float*)d_in[10];
  const float* nn_B    = (const float*)d_in[11];
  const float* nn_W    = (const float*)d_in[12];
  const float* W_ih    = (const float*)d_in[13];
  const float* W_hh    = (const float*)d_in[14];
  const float* b_ih    = (const float*)d_in[15];
  const float* b_hh    = (const float*)d_in[16];

  float* out   = (float*)d_out;
  float* out_h = out;
  float* out_c = out + (size_t)BTOT * HDIM;
  float* out_p = out + (size_t)2 * BTOT * HDIM;

  const size_t flag_bytes = 256;                               // aligned pad
  const size_t qm8_bytes  = (size_t)NHEAD * BTOT * HDIM * 4;   // 4 MB
  const size_t qbg_bytes  = (size_t)BTOT * HDIM * 4;           // 512 KB
  const size_t part_bytes = (size_t)BTOT * 32 * 4;             // 64 KB each
  const size_t need = flag_bytes + qm8_bytes + qbg_bytes + 2 * part_bytes;

  if (ws_size >= need) {
    int*   flagp = (int*)d_ws;
    float* qmw  = (float*)((char*)d_ws + flag_bytes);
    float* qbg  = (float*)((char*)d_ws + flag_bytes + qm8_bytes);
    float* pmax = (float*)((char*)d_ws + flag_bytes + qm8_bytes + qbg_bytes);
    float* psum = (float*)((char*)d_ws + flag_bytes + qm8_bytes + qbg_bytes
                           + part_bytes);

    hipLaunchKernelGGL(k_lstm5, dim3(32, 8), dim3(128), 0, stream,
                       query, state1, state2, W_ih, W_hh, b_ih, b_hh,
                       (const unsigned char*)maskp, flagp, out_h, out_c);
    hipLaunchKernelGGL(k_attn12, dim3(NPP * NHEAD), dim3(512), 0, stream,
                       Kt, Vt, nn_Q, nn_O, maskp, flagp, out_h, qmw);
    hipLaunchKernelGGL(k_qsum, dim3(128), dim3(256), 0, stream,
                       qmw, nn_B, qbg);
    hipLaunchKernelGGL(k_logits7, dim3(NPP * 32), dim3(256), 0, stream,
                       X, varfeat, nn_A, nn_W, qbg, flagp, maskp,
                       pmax, psum);
    hipLaunchKernelGGL(k_choose2, dim3(BTOT), dim3(64), 0, stream,
                       pmax, psum, out_p);
  } else {
    hipLaunchKernelGGL(k_lstm5, dim3(32, 8), dim3(128), 0, stream,
                       query, state1, state2, W_ih, W_hh, b_ih, b_hh,
                       (const unsigned char*)maskp, nullptr, out_h, out_c);
    hipLaunchKernelGGL(k_fused, dim3(NPP * NRR), dim3(256), 0, stream,
                       X, Kt, Vt, varfeat, maskp,
                       nn_Q, nn_O, nn_A, nn_B, nn_W,
                       out_h, out_p);
  }
}

// Round 7
// 228.943 us; speedup vs baseline: 1.6118x; 1.0079x over previous
//
#include <hip/hip_runtime.h>

// Problem constants (from reference) — ALL TENSORS ARE FLOAT32.
#define NPP   64
#define NRR   8
#define NKK   500
#define HDIM  256
#define NHEAD 8
#define VDIM  8
#define HD    32
#define BTOT  512   // NPP*NRR

// ---- fast transcendentals (hardware v_exp_f32 / v_rcp_f32) ----
__device__ __forceinline__ float fast_tanh(float x) {
  const float e = __expf(2.f * x);
  return 1.f - 2.f * __builtin_amdgcn_rcpf(e + 1.f);
}
__device__ __forceinline__ float fast_sig(float x) {
  return __builtin_amdgcn_rcpf(1.f + __expf(-x));
}

// Opaque register copy: output is defined by asm, NOT by a load, so the
// compiler cannot rematerialize it from memory — the value must stay in a
// VGPR from here to its last use.  (Round-6's empty-asm pin failed because
// loads from __restrict const memory were re-issued at use points.)
__device__ __forceinline__ float force_reg(float x) {
  float r;
  asm volatile("v_mov_b32 %0, %1" : "=v"(r) : "v"(x));
  return r;
}
#define FORCE4(v)                                                             \
  { (v).x = force_reg((v).x); (v).y = force_reg((v).y);                       \
    (v).z = force_reg((v).z); (v).w = force_reg((v).w); }

// ===========================================================================
// Kernel 1: LSTM cell GEMM (round-4/6 config).  Tile 32 gate-rows x 64
// batch, 128 thr, 4x4/thread via ds_read_b128; async reg-staged loads.
// Grid 32 x 8.  Block (0,0) probes mask dtype into ws flag.
// ===========================================================================
__global__ __launch_bounds__(128) void k_lstm5(
    const float* __restrict__ query, const float* __restrict__ state1,
    const float* __restrict__ state2,
    const float* __restrict__ W_ih, const float* __restrict__ W_hh,
    const float* __restrict__ b_ih, const float* __restrict__ b_hh,
    const unsigned char* __restrict__ maskb, int* __restrict__ flagp,
    float* __restrict__ out_h, float* __restrict__ out_c)
{
  __shared__ float Wt[32][36];   // [k][gate-row]   4.6 KB
  __shared__ float At[32][68];   // [k][batch-col]  8.7 KB
  __shared__ float gt[32][68];   // gate exchange   8.7 KB

  const int t  = threadIdx.x;    // 128
  const int hb = blockIdx.x;     // 32 tiles of 8 h (x4 gate parts)
  const int bb = blockIdx.y;     // 8 batch tiles of 64

  if (flagp != nullptr && hb == 0 && bb == 0) {
    __shared__ int f;
    if (t == 0) f = 0;
    __syncthreads();
    int any = 0;
    for (int j = t; j < 2048; j += 128) any |= maskb[2 * j + 1];
    if (any) atomicOr(&f, 1);
    __syncthreads();
    if (t == 0) *flagp = f;
  }

  const int tr = t >> 4;                 // 0..7   -> gate-rows tr*4..+3
  const int tc = t & 15;                 // 0..15  -> batch    tc*4..+3

  const int grow = t >> 2;               // 0..31 local gate-row
  const int kseg = t & 3;                // k-quarter (8 floats)
  const int wgrow = (grow >> 3) * HDIM + hb * 8 + (grow & 7);
  const int agrow0 = bb * 64 + grow;     // batch rows grow, grow+32
  const int agrow1 = agrow0 + 32;

  float4 wr0, wr1, ar0, ar1, ar2, ar3;

#define LSTM_ISSUE(K0)                                                        \
  {                                                                           \
    const int k0_ = (K0);                                                     \
    const float* wsrc = (k0_ < 256)                                           \
        ? (W_ih + (size_t)wgrow * HDIM + k0_)                                 \
        : (W_hh + (size_t)wgrow * HDIM + (k0_ - 256));                        \
    wr0 = *reinterpret_cast<const float4*>(wsrc + kseg * 8);                  \
    wr1 = *reinterpret_cast<const float4*>(wsrc + kseg * 8 + 4);              \
    const float* asrc0 = (k0_ < 256)                                          \
        ? (query  + (size_t)agrow0 * HDIM + k0_)                              \
        : (state1 + (size_t)agrow0 * HDIM + (k0_ - 256));                     \
    ar0 = *reinterpret_cast<const float4*>(asrc0 + kseg * 8);                 \
    ar1 = *reinterpret_cast<const float4*>(asrc0 + kseg * 8 + 4);             \
    const float* asrc1 = (k0_ < 256)                                          \
        ? (query  + (size_t)agrow1 * HDIM + k0_)                              \
        : (state1 + (size_t)agrow1 * HDIM + (k0_ - 256));                     \
    ar2 = *reinterpret_cast<const float4*>(asrc1 + kseg * 8);                 \
    ar3 = *reinterpret_cast<const float4*>(asrc1 + kseg * 8 + 4);             \
  }

#define LSTM_WRITE()                                                          \
  {                                                                           \
    const float w0[4] = {wr0.x, wr0.y, wr0.z, wr0.w};                         \
    const float w1[4] = {wr1.x, wr1.y, wr1.z, wr1.w};                         \
    const float a0[4] = {ar0.x, ar0.y, ar0.z, ar0.w};                         \
    const float a1[4] = {ar1.x, ar1.y, ar1.z, ar1.w};                         \
    const float a2[4] = {ar2.x, ar2.y, ar2.z, ar2.w};                         \
    const float a3[4] = {ar3.x, ar3.y, ar3.z, ar3.w};                         \
    _Pragma("unroll")                                                         \
    for (int i = 0; i < 4; ++i) {                                             \
      Wt[kseg * 8 + i][grow]     = w0[i];                                     \
      Wt[kseg * 8 + 4 + i][grow] = w1[i];                                     \
      At[kseg * 8 + i][grow]     = a0[i];                                     \
      At[kseg * 8 + 4 + i][grow] = a1[i];                                     \
      At[kseg * 8 + i][grow + 32]     = a2[i];                                \
      At[kseg * 8 + 4 + i][grow + 32] = a3[i];                                \
    }                                                                         \
  }

  float acc[4][4];
#pragma unroll
  for (int i = 0; i < 4; ++i)
#pragma unroll
    for (int j = 0; j < 4; ++j) acc[i][j] = 0.f;

  LSTM_ISSUE(0);
  LSTM_WRITE();
  __syncthreads();

  for (int k0 = 0; k0 < 512; k0 += 32) {
    const bool more = (k0 + 32) < 512;
    if (more) LSTM_ISSUE(k0 + 32);       // in flight during compute

#pragma unroll 8
    for (int kk = 0; kk < 32; ++kk) {
      const float4 wv = *reinterpret_cast<const float4*>(&Wt[kk][tr * 4]);
      const float4 av = *reinterpret_cast<const float4*>(&At[kk][tc * 4]);
      const float w[4] = {wv.x, wv.y, wv.z, wv.w};
      const float a[4] = {av.x, av.y, av.z, av.w};
#pragma unroll
      for (int i = 0; i < 4; ++i)
#pragma unroll
        for (int j = 0; j < 4; ++j) acc[i][j] += w[i] * a[j];
    }
    __syncthreads();
    if (more) {
      LSTM_WRITE();
      __syncthreads();
    }
  }

#pragma unroll
  for (int i = 0; i < 4; ++i) {
    float4 v;
    v.x = acc[i][0]; v.y = acc[i][1]; v.z = acc[i][2]; v.w = acc[i][3];
    *reinterpret_cast<float4*>(&gt[tr * 4 + i][tc * 4]) = v;
  }
  __syncthreads();

#pragma unroll
  for (int it = 0; it < 4; ++it) {
    const int cell = t + 128 * it;       // 512 cells = 8 h x 64 b
    const int h = cell & 7, b = cell >> 3;
    const int gh = hb * 8 + h;
    const int gb = bb * 64 + b;
    const float bi = b_ih[0 * HDIM + gh] + b_hh[0 * HDIM + gh];
    const float bf = b_ih[1 * HDIM + gh] + b_hh[1 * HDIM + gh];
    const float bg = b_ih[2 * HDIM + gh] + b_hh[2 * HDIM + gh];
    const float bo = b_ih[3 * HDIM + gh] + b_hh[3 * HDIM + gh];
    const float iv = fast_sig (gt[ 0 + h][b] + bi);
    const float fv = fast_sig (gt[ 8 + h][b] + bf);
    const float gv = fast_tanh(gt[16 + h][b] + bg);
    const float ov = fast_sig (gt[24 + h][b] + bo);
    const size_t off = (size_t)gb * HDIM + gh;
    const float c = fv * state2[off] + iv * gv;
    out_c[off] = c;
    out_h[off] = ov * fast_tanh(c);
  }
}

// ===========================================================================
// Kernel 2: attention per (p, head), 512 threads, VGPR cap 128.
// SINGLE CHANGE vs round 6: entry-burst K/V/mask values pass through an
// OPAQUE v_mov asm copy — the compiler cannot rematerialize the loads at
// use points, so K/V/mask are genuinely register-resident for the whole
// kernel and only ONE memory wait exists (at the first barrier).
// ===========================================================================
__global__ __launch_bounds__(512, 4) void k_attn13(
    const float* __restrict__ Kt, const float* __restrict__ Vt,
    const float* __restrict__ nn_Q, const float* __restrict__ nn_O,
    const void* __restrict__ maskp, const int* __restrict__ flagp,
    const float* __restrict__ out_h, float* __restrict__ qm_slabs)
{
  const int p = blockIdx.x >> 3;
  const int a = blockIdx.x & 7;
  const int t = threadIdx.x;
  const int wave = t >> 6, lane = t & 63;

  __shared__ float hs[NRR][HDIM];       // 8 KB
  __shared__ float Qs[NRR][36];         // 1.2 KB
  __shared__ float Sb[NRR][512];        // 16 KB (cols 500..511 = -inf pad)
  __shared__ float pb[8][NRR][HD];      // 8 KB per-wave PV partials
  __shared__ float xs[NRR][36];         // 1.2 KB

  // ---------- entry burst: h, K, V, mask all in flight -------------------
  const float4 hv = reinterpret_cast<const float4*>(
      out_h + (size_t)p * NRR * HDIM)[t];

  const int flag = *flagp;

  const int kc = (t < NKK) ? t : (NKK - 1);
  const float4* kp4 = reinterpret_cast<const float4*>(
      Kt + (((size_t)a * NPP + p) * NKK + kc) * HD);
  float4 kreg[8];
#pragma unroll
  for (int j = 0; j < 8; ++j) kreg[j] = kp4[j];

  const int kg = t >> 3;                // 0..63  k-group
  const int d4p = t & 7;                // f4 dim slot
  float4 v4[8];
  {
    const float* vbase = Vt + ((size_t)a * NPP + p) * NKK * HD + d4p * 4;
#pragma unroll
    for (int j = 0; j < 8; ++j) {
      const int k = kg + 64 * j;
      v4[j] = (k < NKK)
          ? *reinterpret_cast<const float4*>(vbase + (size_t)k * HD)
          : make_float4(0.f, 0.f, 0.f, 0.f);
    }
  }

  float maskv[NRR];
  {
    const unsigned char* mb = (const unsigned char*)maskp;
    const int* mi = (const int*)maskp;
#pragma unroll
    for (int r = 0; r < NRR; ++r) {
      const size_t mo = (size_t)(p * NRR + r) * NKK + kc;
      const bool mk = flag ? (mb[mo] != 0) : (mi[mo] != 0);
      maskv[r] = mk ? -INFINITY : 0.f;
    }
  }

  reinterpret_cast<float4*>(&hs[0][0])[t] = hv;

  // Opaque copies: from here on kreg/v4/maskv are register-resident facts,
  // not re-loadable expressions.  One waitcnt, coinciding with the barrier.
#pragma unroll
  for (int j = 0; j < 8; ++j) { FORCE4(kreg[j]); FORCE4(v4[j]); }
#pragma unroll
  for (int r = 0; r < NRR; ++r) maskv[r] = force_reg(maskv[r]);
  __syncthreads();

  // ---------- Q-proj: wave r; lane = (d4, ks); ks stride 4 ---------------
  {
    const int r = wave;
    const int d4 = lane >> 3, ks = lane & 7;
    float qx = 0.f, qy = 0.f, qz = 0.f, qw = 0.f;
#pragma unroll
    for (int i = 0; i < 8; ++i) {
      const int hb = 32 * i + ks * 4;
      const float4 hv4 = *reinterpret_cast<const float4*>(&hs[r][hb]);
      const float hh[4] = {hv4.x, hv4.y, hv4.z, hv4.w};
      const float* nqb = nn_Q + ((size_t)a * HDIM + hb) * HD + d4 * 4;
#pragma unroll
      for (int jj = 0; jj < 4; ++jj) {
        const float4 wv = *reinterpret_cast<const float4*>(nqb + (size_t)jj * HD);
        qx += hh[jj] * wv.x; qy += hh[jj] * wv.y;
        qz += hh[jj] * wv.z; qw += hh[jj] * wv.w;
      }
    }
#pragma unroll
    for (int off = 1; off < 8; off <<= 1) {
      qx += __shfl_xor(qx, off, 64);
      qy += __shfl_xor(qy, off, 64);
      qz += __shfl_xor(qz, off, 64);
      qw += __shfl_xor(qw, off, 64);
    }
    if (ks == 0) {
      const float sc = 0.17677669529663687f;   // 1/sqrt(32)
      Qs[r][d4 * 4 + 0] = qx * sc; Qs[r][d4 * 4 + 1] = qy * sc;
      Qs[r][d4 * 4 + 2] = qz * sc; Qs[r][d4 * 4 + 3] = qw * sc;
    }
  }
  __syncthreads();

  // ---------- scores from register-resident kreg -------------------------
#pragma unroll
  for (int r = 0; r < NRR; ++r) {
    float s = 0.f;
#pragma unroll
    for (int j = 0; j < 8; ++j) {
      const float4 q = *reinterpret_cast<const float4*>(&Qs[r][j * 4]);
      const float4 k4 = kreg[j];
      s += q.x * k4.x + q.y * k4.y + q.z * k4.z + q.w * k4.w;
    }
    Sb[r][t] = (t < NKK) ? (s + maskv[r]) : -INFINITY;
  }
  __syncthreads();

  // ---------- softmax: wave w -> rollout w -------------------------------
  {
    const int r = wave;
    float lv[8], m = -INFINITY;
#pragma unroll
    for (int i = 0; i < 8; ++i) {
      lv[i] = Sb[r][lane + 64 * i];
      m = fmaxf(m, lv[i]);
    }
#pragma unroll
    for (int off = 32; off > 0; off >>= 1) m = fmaxf(m, __shfl_xor(m, off, 64));
    float ssum = 0.f;
#pragma unroll
    for (int i = 0; i < 8; ++i) {
      lv[i] = __expf(lv[i] - m);
      ssum += lv[i];
    }
#pragma unroll
    for (int off = 32; off > 0; off >>= 1) ssum += __shfl_xor(ssum, off, 64);
    const float inv = 1.f / ssum;
#pragma unroll
    for (int i = 0; i < 8; ++i) Sb[r][lane + 64 * i] = lv[i] * inv;
  }
  __syncthreads();

  // ---------- PV: register-resident V x Sb broadcasts; shfl-reduce -------
  {
    float4 acc4[NRR];
#pragma unroll
    for (int r = 0; r < NRR; ++r) acc4[r] = make_float4(0.f, 0.f, 0.f, 0.f);
#pragma unroll
    for (int j = 0; j < 8; ++j) {
      const float4 v = v4[j];
#pragma unroll
      for (int r = 0; r < NRR; ++r) {
        const float s = Sb[r][kg + 64 * j];   // pad rows are exact 0
        acc4[r].x += s * v.x; acc4[r].y += s * v.y;
        acc4[r].z += s * v.z; acc4[r].w += s * v.w;
      }
    }
#pragma unroll
    for (int off = 8; off < 64; off <<= 1) {
#pragma unroll
      for (int r = 0; r < NRR; ++r) {
        acc4[r].x += __shfl_xor(acc4[r].x, off, 64);
        acc4[r].y += __shfl_xor(acc4[r].y, off, 64);
        acc4[r].z += __shfl_xor(acc4[r].z, off, 64);
        acc4[r].w += __shfl_xor(acc4[r].w, off, 64);
      }
    }
    if (lane < 8) {
#pragma unroll
      for (int r = 0; r < NRR; ++r)
        *reinterpret_cast<float4*>(&pb[wave][r][lane * 4]) = acc4[r];
    }
  }
  __syncthreads();

  if (t < 256) {
    const int r = t >> 5, d = t & 31;
    float s = 0.f;
#pragma unroll
    for (int w = 0; w < 8; ++w) s += pb[w][r][d];
    xs[r][d] = s;
  }
  __syncthreads();

  // ---------- O-proj -> per-head slab ------------------------------------
  {
    const int j8 = t & 255;
    const int rr = t >> 8;                // row-group {0..3} or {4..7}
    const float* ob = nn_O + (size_t)(a * HD) * HDIM + j8;
    float a0 = 0.f, a1 = 0.f, a2 = 0.f, a3 = 0.f;
#pragma unroll
    for (int d4 = 0; d4 < 8; ++d4) {
      const float4 x0 = *reinterpret_cast<const float4*>(&xs[rr * 4 + 0][d4 * 4]);
      const float4 x1 = *reinterpret_cast<const float4*>(&xs[rr * 4 + 1][d4 * 4]);
      const float4 x2 = *reinterpret_cast<const float4*>(&xs[rr * 4 + 2][d4 * 4]);
      const float4 x3 = *reinterpret_cast<const float4*>(&xs[rr * 4 + 3][d4 * 4]);
      const float c0[4] = {x0.x, x0.y, x0.z, x0.w};
      const float c1[4] = {x1.x, x1.y, x1.z, x1.w};
      const float c2[4] = {x2.x, x2.y, x2.z, x2.w};
      const float c3[4] = {x3.x, x3.y, x3.z, x3.w};
#pragma unroll
      for (int dd = 0; dd < 4; ++dd) {
        const float w = ob[(size_t)(d4 * 4 + dd) * HDIM];
        a0 += c0[dd] * w; a1 += c1[dd] * w;
        a2 += c2[dd] * w; a3 += c3[dd] * w;
      }
    }
    float* slab = qm_slabs + (size_t)a * BTOT * HDIM;
    slab[(size_t)(p * NRR + rr * 4 + 0) * HDIM + j8] = a0;
    slab[(size_t)(p * NRR + rr * 4 + 1) * HDIM + j8] = a1;
    slab[(size_t)(p * NRR + rr * 4 + 2) * HDIM + j8] = a2;
    slab[(size_t)(p * NRR + rr * 4 + 3) * HDIM + j8] = a3;
  }
}

// ===========================================================================
// Kernel 3: qbg[512][256] = sum_a qm_slab[a] + nn_B.  Grid 128 x 256 thr.
// ===========================================================================
__global__ __launch_bounds__(256) void k_qsum(
    const float* __restrict__ qm_slabs, const float* __restrict__ nn_B,
    float* __restrict__ qbg)
{
  const int idx = blockIdx.x * 256 + threadIdx.x;   // 32768 f4 slots
  const int row = idx >> 6, h4 = idx & 63;
  float4 acc = *reinterpret_cast<const float4*>(nn_B + h4 * 4);
#pragma unroll
  for (int a = 0; a < NHEAD; ++a) {
    const float4 q = *reinterpret_cast<const float4*>(
        qm_slabs + (size_t)a * BTOT * HDIM + (size_t)row * HDIM + h4 * 4);
    acc.x += q.x; acc.y += q.y; acc.z += q.z; acc.w += q.w;
  }
  *reinterpret_cast<float4*>(qbg + (size_t)row * HDIM + h4 * 4) = acc;
}

// ===========================================================================
// Kernel 4: additive logits + per-(row, kt) softmax partials.
// Grid 64 x 32.  Wave owns 4 k; lane owns 4 h.
// ===========================================================================
__global__ __launch_bounds__(256) void k_logits7(
    const float* __restrict__ X, const float* __restrict__ varfeat,
    const float* __restrict__ nn_A, const float* __restrict__ nn_W,
    const float* __restrict__ qbg,
    const int* __restrict__ flagp, const void* __restrict__ maskp,
    float* __restrict__ pmax, float* __restrict__ psum)
{
  const int p  = blockIdx.x >> 5;
  const int kt = blockIdx.x & 31;
  const int t = threadIdx.x;
  const int wave = t >> 6, lane = t & 63;
  const int h0 = lane * 4;

  __shared__ float red[4][NRR][2];      // per-wave (max, sum) partials

  const unsigned char* mb = (const unsigned char*)maskp;
  const int* mi = (const int*)maskp;
  const int flag = *flagp;
  const bool mbyte = (flag != 0);

  const float4 w4 = *reinterpret_cast<const float4*>(nn_W + h0);
  float4 a4r[VDIM];
#pragma unroll
  for (int v = 0; v < VDIM; ++v)
    a4r[v] = *reinterpret_cast<const float4*>(nn_A + (size_t)v * HDIM + h0);
  float4 q4r[NRR];
#pragma unroll
  for (int r = 0; r < NRR; ++r)
    q4r[r] = *reinterpret_cast<const float4*>(
        qbg + (size_t)(p * NRR + r) * HDIM + h0);

  float rmax = -INFINITY, rsum = 0.f;    // valid at lanes with (lane&7)==0

  for (int kk = 0; kk < 4; ++kk) {
    const int k = kt * 16 + wave * 4 + kk;
    if (k >= NKK) break;   // wave-uniform

    const float4 x4 = *reinterpret_cast<const float4*>(
        X + ((size_t)p * NKK + k) * HDIM + h0);
    float base0 = x4.x, base1 = x4.y, base2 = x4.z, base3 = x4.w;
#pragma unroll
    for (int v = 0; v < VDIM; ++v) {
      const float vv = varfeat[((size_t)p * VDIM + v) * NKK + k];
      base0 += vv * a4r[v].x; base1 += vv * a4r[v].y;
      base2 += vv * a4r[v].z; base3 += vv * a4r[v].w;
    }

    float acc[NRR];
#pragma unroll
    for (int r = 0; r < NRR; ++r) {
      acc[r] = fast_tanh(base0 + q4r[r].x) * w4.x
             + fast_tanh(base1 + q4r[r].y) * w4.y
             + fast_tanh(base2 + q4r[r].z) * w4.z
             + fast_tanh(base3 + q4r[r].w) * w4.w;
    }

    // multi-value wave reduction: 8 sums across 64 lanes
    float v4r[4];
    {
      float sw[8];
#pragma unroll
      for (int j = 0; j < 8; ++j) sw[j] = __shfl_xor(acc[j], 32, 64);
      const bool hi = (lane & 32) != 0;
#pragma unroll
      for (int j = 0; j < 4; ++j)
        v4r[j] = hi ? (acc[j + 4] + sw[j + 4]) : (acc[j] + sw[j]);
    }
    float v2[2];
    {
      float sw[4];
#pragma unroll
      for (int j = 0; j < 4; ++j) sw[j] = __shfl_xor(v4r[j], 16, 64);
      const bool hi = (lane & 16) != 0;
      v2[0] = hi ? (v4r[2] + sw[2]) : (v4r[0] + sw[0]);
      v2[1] = hi ? (v4r[3] + sw[3]) : (v4r[1] + sw[1]);
    }
    float w;
    {
      const float s0 = __shfl_xor(v2[0], 8, 64);
      const float s1 = __shfl_xor(v2[1], 8, 64);
      w = ((lane & 8) != 0) ? (v2[1] + s1) : (v2[0] + s0);
    }
    w += __shfl_xor(w, 4, 64);
    w += __shfl_xor(w, 2, 64);
    w += __shfl_xor(w, 1, 64);

    if ((lane & 7) == 0) {
      const int r = lane >> 3;
      const size_t mrow = (size_t)(p * NRR + r) * NKK + k;
      const bool mk = mbyte ? (mb[mrow] != 0) : (mi[mrow] != 0);
      const float l = mk ? -INFINITY : fast_tanh(w) * 10.0f;
      rmax = fmaxf(rmax, l);
      rsum += __expf(l - 10.f);          // exp(-inf) = 0 for masked
    }
  }

  if ((lane & 7) == 0) {
    red[wave][lane >> 3][0] = rmax;
    red[wave][lane >> 3][1] = rsum;
  }
  __syncthreads();
  if (t < NRR) {
    float m = red[0][t][0], s = red[0][t][1];
#pragma unroll
    for (int w = 1; w < 4; ++w) {
      m = fmaxf(m, red[w][t][0]);
      s += red[w][t][1];
    }
    pmax[(size_t)(p * NRR + t) * 32 + kt] = m;
    psum[(size_t)(p * NRR + t) * 32 + kt] = s;
  }
}

// ===========================================================================
// Kernel 5: choose.  One wave per batch row; reduce the 32 kt-partials.
// chosen_p = m - LSE = m - 10 - log(sum exp(l-10)).
// ===========================================================================
__global__ __launch_bounds__(64) void k_choose2(
    const float* __restrict__ pmax, const float* __restrict__ psum,
    float* __restrict__ out_p)
{
  const int b = blockIdx.x;
  const int lane = threadIdx.x;
  float m = (lane < 32) ? pmax[(size_t)b * 32 + lane] : -INFINITY;
  float s = (lane < 32) ? psum[(size_t)b * 32 + lane] : 0.f;
#pragma unroll
  for (int off = 16; off > 0; off >>= 1) {
    m = fmaxf(m, __shfl_xor(m, off, 64));
    s += __shfl_xor(s, off, 64);
  }
  if (lane == 0) out_p[b] = m - 10.f - logf(s);
}

// ===========================================================================
// Fallback (ws too small): fused kernel — known-correct.
// ===========================================================================
__global__ __launch_bounds__(256) void k_fused(
    const float* __restrict__ X, const float* __restrict__ Kt,
    const float* __restrict__ Vt, const float* __restrict__ varfeat,
    const void* __restrict__ maskp,
    const float* __restrict__ nn_Q, const float* __restrict__ nn_O,
    const float* __restrict__ nn_A, const float* __restrict__ nn_B,
    const float* __restrict__ nn_W,
    const float* __restrict__ out_h, float* __restrict__ out_p)
{
  const int p = blockIdx.x >> 3;
  const int r = blockIdx.x & 7;
  const int t = threadIdx.x;
  const int wave = t >> 6, lane = t & 63;

  __shared__ float hs[HDIM];
  __shared__ float Qs[NHEAD][HD];
  __shared__ float Sb[NHEAD][NKK];
  __shared__ float xs[HDIM];
  __shared__ float qs[HDIM];
  __shared__ float As2[HDIM][VDIM];
  __shared__ float Ws[HDIM];
  __shared__ float lsb[NKK];
  __shared__ int   mask_any;

  const unsigned char* mb = (const unsigned char*)maskp;
  if (t == 0) mask_any = 0;
  __syncthreads();
  {
    int any = 0;
    for (int j = t; j < 2048; j += 256) any |= mb[2 * j + 1];
    if (any) atomicOr(&mask_any, 1);
  }
  for (int idx = t; idx < VDIM * HDIM; idx += 256)
    As2[idx & 255][idx >> 8] = nn_A[idx];
  Ws[t] = nn_W[t];
  hs[t] = out_h[(size_t)(p * NRR + r) * HDIM + t];
  __syncthreads();
  const bool mbyte = (mask_any != 0);
  const int* mi = (const int*)maskp;
  const size_t mrow = (size_t)(p * NRR + r) * NKK;
  {
    const int a = t >> 5, d = t & 31;
    const float* nq = nn_Q + (size_t)a * HDIM * HD + d;
    float acc = 0.f;
    for (int h = 0; h < HDIM; ++h) acc += hs[h] * nq[(size_t)h * HD];
    Qs[a][d] = acc * 0.17677669529663687f;
  }
  __syncthreads();
  for (int k = t; k < NKK; k += 256) {
    const bool mk = mbyte ? (mb[mrow + k] != 0) : (mi[mrow + k] != 0);
#pragma unroll
    for (int a = 0; a < NHEAD; ++a) {
      const float4* kr4 = reinterpret_cast<const float4*>(
          Kt + (((size_t)a * NPP + p) * NKK + k) * HD);
      float s = 0.f;
#pragma unroll
      for (int d4 = 0; d4 < HD / 4; ++d4) {
        const float4 u = kr4[d4];
        s += Qs[a][4 * d4] * u.x + Qs[a][4 * d4 + 1] * u.y
           + Qs[a][4 * d4 + 2] * u.z + Qs[a][4 * d4 + 3] * u.w;
      }
      Sb[a][k] = mk ? -INFINITY : s;
    }
  }
  __syncthreads();
  for (int aa = 0; aa < 2; ++aa) {
    const int a = wave * 2 + aa;
    float m = -INFINITY;
    for (int k = lane; k < NKK; k += 64) m = fmaxf(m, Sb[a][k]);
#pragma unroll
    for (int off = 32; off > 0; off >>= 1) m = fmaxf(m, __shfl_xor(m, off, 64));
    float ssum = 0.f;
    for (int k = lane; k < NKK; k += 64) {
      const float e = expf(Sb[a][k] - m);
      Sb[a][k] = e; ssum += e;
    }
#pragma unroll
    for (int off = 32; off > 0; off >>= 1) ssum += __shfl_xor(ssum, off, 64);
    const float inv = 1.f / ssum;
    for (int k = lane; k < NKK; k += 64) Sb[a][k] *= inv;
  }
  __syncthreads();
  {
    const int a = t >> 5, d = t & 31;
    const float* vb = Vt + ((size_t)a * NPP + p) * NKK * HD + d;
    float acc = 0.f;
    for (int k = 0; k < NKK; ++k) acc += Sb[a][k] * vb[(size_t)k * HD];
    xs[a * HD + d] = acc;
  }
  __syncthreads();
  {
    float acc = 0.f;
    for (int i = 0; i < HDIM; ++i) acc += xs[i] * nn_O[(size_t)i * HDIM + t];
    qs[t] = acc + nn_B[t];
  }
  __syncthreads();
  for (int k = t; k < NKK; k += 256) {
    float vfv[VDIM];
#pragma unroll
    for (int v = 0; v < VDIM; ++v)
      vfv[v] = varfeat[((size_t)p * VDIM + v) * NKK + k];
    const float4* xp4 = reinterpret_cast<const float4*>(
        X + ((size_t)p * NKK + k) * HDIM);
    float acc = 0.f;
    for (int h4 = 0; h4 < HDIM / 4; ++h4) {
      const float4 ux = xp4[h4];
      const float xv[4] = {ux.x, ux.y, ux.z, ux.w};
#pragma unroll
      for (int j = 0; j < 4; ++j) {
        const int h = 4 * h4 + j;
        float base = xv[j] + qs[h];
        const float4 a0 = *reinterpret_cast<const float4*>(&As2[h][0]);
        const float4 a1 = *reinterpret_cast<const float4*>(&As2[h][4]);
        base += vfv[0] * a0.x + vfv[1] * a0.y + vfv[2] * a0.z + vfv[3] * a0.w
              + vfv[4] * a1.x + vfv[5] * a1.y + vfv[6] * a1.z + vfv[7] * a1.w;
        acc += tanhf(base) * Ws[h];
      }
    }
    lsb[k] = acc;
  }
  __syncthreads();
  for (int k = t; k < NKK; k += 256) {
    const bool mk = mbyte ? (mb[mrow + k] != 0) : (mi[mrow + k] != 0);
    lsb[k] = mk ? -INFINITY : tanhf(lsb[k]) * 10.0f;
  }
  __syncthreads();
  if (wave == 0) {
    float m = -INFINITY;
    for (int k = lane; k < NKK; k += 64) m = fmaxf(m, lsb[k]);
#pragma unroll
    for (int off = 32; off > 0; off >>= 1) m = fmaxf(m, __shfl_xor(m, off, 64));
    float s = 0.f;
    for (int k = lane; k < NKK; k += 64) s += expf(lsb[k] - m);
#pragma unroll
    for (int off = 32; off > 0; off >>= 1) s += __shfl_xor(s, off, 64);
    if (lane == 0) out_p[p * NRR + r] = -logf(s);
  }
}

// ===========================================================================
extern "C" void kernel_launch(void* const* d_in, const int* in_sizes, int n_in,
                              void* d_out, int out_size, void* d_ws, size_t ws_size,
                              hipStream_t stream)
{
  const float* X       = (const float*)d_in[0];
  const float* Kt      = (const float*)d_in[1];
  const float* Vt      = (const float*)d_in[2];
  const float* query   = (const float*)d_in[3];
  const float* state1  = (const float*)d_in[4];
  const float* state2  = (const float*)d_in[5];
  const float* varfeat = (const float*)d_in[6];
  const void*  maskp   = d_in[7];
  const float* nn_Q    = (const float*)d_in[8];
  const float* nn_O    = (const float*)d_in[9];
  const float* nn_A    = (const float*)d_in[10];
  const float* nn_B    = (const float*)d_in[11];
  const float* nn_W    = (const float*)d_in[12];
  const float* W_ih    = (const float*)d_in[13];
  const float* W_hh    = (const float*)d_in[14];
  const float* b_ih    = (const float*)d_in[15];
  const float* b_hh    = (const float*)d_in[16];

  float* out   = (float*)d_out;
  float* out_h = out;
  float* out_c = out + (size_t)BTOT * HDIM;
  float* out_p = out + (size_t)2 * BTOT * HDIM;

  const size_t flag_bytes = 256;                               // aligned pad
  const size_t qm8_bytes  = (size_t)NHEAD * BTOT * HDIM * 4;   // 4 MB
  const size_t qbg_bytes  = (size_t)BTOT * HDIM * 4;           // 512 KB
  const size_t part_bytes = (size_t)BTOT * 32 * 4;             // 64 KB each
  const size_t need = flag_bytes + qm8_bytes + qbg_bytes + 2 * part_bytes;

  if (ws_size >= need) {
    int*   flagp = (int*)d_ws;
    float* qmw  = (float*)((char*)d_ws + flag_bytes);
    float* qbg  = (float*)((char*)d_ws + flag_bytes + qm8_bytes);
    float* pmax = (float*)((char*)d_ws + flag_bytes + qm8_bytes + qbg_bytes);
    float* psum = (float*)((char*)d_ws + flag_bytes + qm8_bytes + qbg_bytes
                           + part_bytes);

    hipLaunchKernelGGL(k_lstm5, dim3(32, 8), dim3(128), 0, stream,
                       query, state1, state2, W_ih, W_hh, b_ih, b_hh,
                       (const unsigned char*)maskp, flagp, out_h, out_c);
    hipLaunchKernelGGL(k_attn13, dim3(NPP * NHEAD), dim3(512), 0, stream,
                       Kt, Vt, nn_Q, nn_O, maskp, flagp, out_h, qmw);
    hipLaunchKernelGGL(k_qsum, dim3(128), dim3(256), 0, stream,
                       qmw, nn_B, qbg);
    hipLaunchKernelGGL(k_logits7, dim3(NPP * 32), dim3(256), 0, stream,
                       X, varfeat, nn_A, nn_W, qbg, flagp, maskp,
                       pmax, psum);
    hipLaunchKernelGGL(k_choose2, dim3(BTOT), dim3(64), 0, stream,
                       pmax, psum, out_p);
  } else {
    hipLaunchKernelGGL(k_lstm5, dim3(32, 8), dim3(128), 0, stream,
                       query, state1, state2, W_ih, W_hh, b_ih, b_hh,
                       (const unsigned char*)maskp, nullptr, out_h, out_c);
    hipLaunchKernelGGL(k_fused, dim3(NPP * NRR), dim3(256), 0, stream,
                       X, Kt, Vt, varfeat, maskp,
                       nn_Q, nn_O, nn_A, nn_B, nn_W,
                       out_h, out_p);
  }
}

// Round 8
// 223.323 us; speedup vs baseline: 1.6524x; 1.0252x over previous
//
#include <hip/hip_runtime.h>

// Problem constants (from reference) — ALL TENSORS ARE FLOAT32.
#define NPP   64
#define NRR   8
#define NKK   500
#define HDIM  256
#define NHEAD 8
#define VDIM  8
#define HD    32
#define BTOT  512   // NPP*NRR

// ---- fast transcendentals (hardware v_exp_f32 / v_rcp_f32) ----
__device__ __forceinline__ float fast_tanh(float x) {
  const float e = __expf(2.f * x);
  return 1.f - 2.f * __builtin_amdgcn_rcpf(e + 1.f);
}
__device__ __forceinline__ float fast_sig(float x) {
  return __builtin_amdgcn_rcpf(1.f + __expf(-x));
}

// ===========================================================================
// Kernel 1: LSTM cell, tiled GEMM, 32 gate-rows x 32 batch tiles.
// Block (0,0) additionally probes the mask dtype into ws flag (int32 mask
// has all-zero odd bytes in the first 4 KB; 10%-dense bool mask does not).
// ===========================================================================
__global__ __launch_bounds__(256) void k_lstm3(
    const float* __restrict__ query, const float* __restrict__ state1,
    const float* __restrict__ state2,
    const float* __restrict__ W_ih, const float* __restrict__ W_hh,
    const float* __restrict__ b_ih, const float* __restrict__ b_hh,
    const unsigned char* __restrict__ maskb, int* __restrict__ flagp,
    float* __restrict__ out_h, float* __restrict__ out_c)
{
  __shared__ float Wt[32][33];
  __shared__ float At[32][33];
  __shared__ float gt[32][33];

  const int t  = threadIdx.x;
  const int hb = blockIdx.x;
  const int bb = blockIdx.y;

  if (flagp != nullptr && hb == 0 && bb == 0) {
    __shared__ int f;
    if (t == 0) f = 0;
    __syncthreads();
    int any = 0;
    for (int j = t; j < 2048; j += 256) any |= maskb[2 * j + 1];
    if (any) atomicOr(&f, 1);
    __syncthreads();
    if (t == 0) *flagp = f;
  }

  const int trow = t >> 4;
  const int tcol = t & 15;

  float acc00 = 0.f, acc01 = 0.f, acc10 = 0.f, acc11 = 0.f;

  const int wrow = t >> 3, wk4 = t & 7;
  const int wpart = wrow >> 3, whh = wrow & 7;
  const int wgrow = wpart * HDIM + hb * 8 + whh;
  const int agrow = bb * 32 + wrow;

  for (int k0 = 0; k0 < 512; k0 += 32) {
    __syncthreads();
    {
      const float* wsrc = (k0 < 256) ? (W_ih + (size_t)wgrow * HDIM + k0)
                                     : (W_hh + (size_t)wgrow * HDIM + (k0 - 256));
      const float4 wv = *reinterpret_cast<const float4*>(wsrc + wk4 * 4);
      Wt[wk4 * 4 + 0][wrow] = wv.x; Wt[wk4 * 4 + 1][wrow] = wv.y;
      Wt[wk4 * 4 + 2][wrow] = wv.z; Wt[wk4 * 4 + 3][wrow] = wv.w;

      const float* asrc = (k0 < 256) ? (query  + (size_t)agrow * HDIM + k0)
                                     : (state1 + (size_t)agrow * HDIM + (k0 - 256));
      const float4 av = *reinterpret_cast<const float4*>(asrc + wk4 * 4);
      At[wk4 * 4 + 0][wrow] = av.x; At[wk4 * 4 + 1][wrow] = av.y;
      At[wk4 * 4 + 2][wrow] = av.z; At[wk4 * 4 + 3][wrow] = av.w;
    }
    __syncthreads();

#pragma unroll 8
    for (int kk = 0; kk < 32; ++kk) {
      const float w0 = Wt[kk][trow], w1 = Wt[kk][trow + 16];
      const float a0 = At[kk][tcol], a1 = At[kk][tcol + 16];
      acc00 += w0 * a0; acc01 += w0 * a1;
      acc10 += w1 * a0; acc11 += w1 * a1;
    }
  }

  gt[trow][tcol] = acc00;      gt[trow][tcol + 16] = acc01;
  gt[trow + 16][tcol] = acc10; gt[trow + 16][tcol + 16] = acc11;
  __syncthreads();

  {
    const int h = t & 7, b = t >> 3;
    const int gh = hb * 8 + h;
    const int gb = bb * 32 + b;
    const float bi = b_ih[0 * HDIM + gh] + b_hh[0 * HDIM + gh];
    const float bf = b_ih[1 * HDIM + gh] + b_hh[1 * HDIM + gh];
    const float bg = b_ih[2 * HDIM + gh] + b_hh[2 * HDIM + gh];
    const float bo = b_ih[3 * HDIM + gh] + b_hh[3 * HDIM + gh];
    const float iv = fast_sig (gt[ 0 + h][b] + bi);
    const float fv = fast_sig (gt[ 8 + h][b] + bf);
    const float gv = fast_tanh(gt[16 + h][b] + bg);
    const float ov = fast_sig (gt[24 + h][b] + bo);
    const size_t off = (size_t)gb * HDIM + gh;
    const float c = fv * state2[off] + iv * gv;
    out_c[off] = c;
    out_h[off] = ov * fast_tanh(c);
  }
}

// ===========================================================================
// Kernel 2: attention per (p, head), 1024 thr.  REGISTER PREFETCH: K, V and
// mask loads are issued at block entry (addresses are block-static) and
// consumed phases later — global latency hides behind Q-proj/softmax.
// qm written as per-head slabs (use_slabs=1, no atomics/memset) or via
// atomicAdd into a single zeroed buffer (use_slabs=0).
// ===========================================================================
__global__ __launch_bounds__(1024) void k_attn6(
    const float* __restrict__ Kt, const float* __restrict__ Vt,
    const float* __restrict__ nn_Q, const float* __restrict__ nn_O,
    const void* __restrict__ maskp, const int* __restrict__ flagp,
    const float* __restrict__ out_h, float* __restrict__ qmw, int use_slabs)
{
  const int p = blockIdx.x >> 3;
  const int a = blockIdx.x & 7;
  const int t = threadIdx.x;
  const int wave = t >> 6, lane = t & 63;

  __shared__ float hs[NRR][HDIM];     // 8 KB
  __shared__ float buf[HDIM * 33];    // 33.8 KB: nn_Q staged; reused as xp
  __shared__ float Qs[NRR][HD];       // 1 KB
  __shared__ float Sb[NRR][NKK];      // 16 KB (first 4 KB doubles as qp)
  __shared__ float xs[NRR][HD];       // 1 KB

  const unsigned char* mb = (const unsigned char*)maskp;
  const int* mi = (const int*)maskp;

  // ---------- 1) staging loads first (their waits must not drain K/V) ----
  float4 hv = make_float4(0.f, 0.f, 0.f, 0.f);
  if (t < 512)
    hv = reinterpret_cast<const float4*>(out_h + (size_t)p * NRR * HDIM)[t];
  const float4* nq4 = reinterpret_cast<const float4*>(nn_Q + (size_t)a * HDIM * HD);
  const float4 q0 = nq4[t];
  const float4 q1 = nq4[t + 1024];

  // ---------- 2) flag, then K / V / mask prefetch ------------------------
  const int flag = *flagp;

  const int k2 = t >> 1, dh = t & 1;          // scores mapping
  const int kc = (k2 < NKK) ? k2 : (NKK - 1);
  const float4 kreg = *reinterpret_cast<const float4*>(
      Kt + (((size_t)a * NPP + p) * NKK + kc) * HD + dh * 16);

  const int dpv = t & 31, kspv = t >> 5;      // PV mapping
  const float* vb = Vt + ((size_t)a * NPP + p) * NKK * HD + dpv;
  float vreg[16];
#pragma unroll
  for (int j = 0; j < 15; ++j) vreg[j] = vb[(size_t)(kspv + 32 * j) * HD];
  vreg[15] = (kspv < NKK - 480) ? vb[(size_t)(kspv + 480) * HD] : 0.f;

  float maskval[NRR];                          // 0 or -inf, scores mapping
#pragma unroll
  for (int r = 0; r < NRR; ++r) maskval[r] = 0.f;
  if (dh == 0 && k2 < NKK) {
    if (flag) {
#pragma unroll
      for (int r = 0; r < NRR; ++r)
        maskval[r] = mb[(size_t)(p * NRR + r) * NKK + k2] ? -INFINITY : 0.f;
    } else {
#pragma unroll
      for (int r = 0; r < NRR; ++r)
        maskval[r] = mi[(size_t)(p * NRR + r) * NKK + k2] ? -INFINITY : 0.f;
    }
  }

  // ---------- 3) LDS staging (waits only on h/nn_Q; K/V stay in flight) --
  if (t < 512) reinterpret_cast<float4*>(&hs[0][0])[t] = hv;
  {
    const int h0 = t >> 3, d40 = t & 7;
    buf[h0 * 33 + d40 * 4 + 0] = q0.x; buf[h0 * 33 + d40 * 4 + 1] = q0.y;
    buf[h0 * 33 + d40 * 4 + 2] = q0.z; buf[h0 * 33 + d40 * 4 + 3] = q0.w;
    const int h1 = (t + 1024) >> 3, d41 = t & 7;
    buf[h1 * 33 + d41 * 4 + 0] = q1.x; buf[h1 * 33 + d41 * 4 + 1] = q1.y;
    buf[h1 * 33 + d41 * 4 + 2] = q1.z; buf[h1 * 33 + d41 * 4 + 3] = q1.w;
  }
  __syncthreads();

  // ---------- Q-proj, 4-way h-split --------------------------------------
  {
    const int r = t >> 7, d = (t >> 2) & 31, c = t & 3;
    float acc = 0.f;
#pragma unroll 8
    for (int h = c * 64; h < c * 64 + 64; ++h)
      acc += hs[r][h] * buf[h * 33 + d];
    float* qp = &Sb[0][0];
    qp[((r * HD) + d) * 4 + c] = acc;
  }
  __syncthreads();
  if (t < 256) {
    const int r = t >> 5, d = t & 31;
    const float* qp = &Sb[0][0];
    Qs[r][d] = (qp[(r * HD + d) * 4 + 0] + qp[(r * HD + d) * 4 + 1]
              + qp[(r * HD + d) * 4 + 2] + qp[(r * HD + d) * 4 + 3])
             * 0.17677669529663687f;
  }
  __syncthreads();

  // ---------- scores from prefetched kreg --------------------------------
  {
    float sc[NRR];
#pragma unroll
    for (int r = 0; r < NRR; ++r) sc[r] = 0.f;
    {
      const float4 u = kreg;
#pragma unroll
      for (int r = 0; r < NRR; ++r) {
        sc[r] += Qs[r][dh * 16 + 0] * u.x + Qs[r][dh * 16 + 1] * u.y
               + Qs[r][dh * 16 + 2] * u.z + Qs[r][dh * 16 + 3] * u.w;
      }
    }
    // remaining 12 of 16 dims: loaded here (L2-hot, issued together)
    const float4* kr4 = reinterpret_cast<const float4*>(
        Kt + (((size_t)a * NPP + p) * NKK + kc) * HD + dh * 16);
    const float4 u1 = kr4[1], u2 = kr4[2], u3 = kr4[3];
#pragma unroll
    for (int r = 0; r < NRR; ++r) {
      sc[r] += Qs[r][dh * 16 +  4] * u1.x + Qs[r][dh * 16 +  5] * u1.y
             + Qs[r][dh * 16 +  6] * u1.z + Qs[r][dh * 16 +  7] * u1.w
             + Qs[r][dh * 16 +  8] * u2.x + Qs[r][dh * 16 +  9] * u2.y
             + Qs[r][dh * 16 + 10] * u2.z + Qs[r][dh * 16 + 11] * u2.w
             + Qs[r][dh * 16 + 12] * u3.x + Qs[r][dh * 16 + 13] * u3.y
             + Qs[r][dh * 16 + 14] * u3.z + Qs[r][dh * 16 + 15] * u3.w;
    }
#pragma unroll
    for (int r = 0; r < NRR; ++r) sc[r] += __shfl_xor(sc[r], 1, 64);
    if (dh == 0 && k2 < NKK) {
#pragma unroll
      for (int r = 0; r < NRR; ++r)
        Sb[r][k2] = sc[r] + maskval[r];      // finite + (-inf) = -inf
    }
  }
  __syncthreads();

  // ---------- softmax: wave w (< 8) -> rollout w -------------------------
  if (wave < NRR) {
    const int r = wave;
    float m = -INFINITY;
    for (int k = lane; k < NKK; k += 64) m = fmaxf(m, Sb[r][k]);
#pragma unroll
    for (int off = 32; off > 0; off >>= 1) m = fmaxf(m, __shfl_xor(m, off, 64));
    float ssum = 0.f;
    for (int k = lane; k < NKK; k += 64) {
      const float e = __expf(Sb[r][k] - m);
      Sb[r][k] = e;
      ssum += e;
    }
#pragma unroll
    for (int off = 32; off > 0; off >>= 1) ssum += __shfl_xor(ssum, off, 64);
    const float inv = 1.f / ssum;
    for (int k = lane; k < NKK; k += 64) Sb[r][k] *= inv;
  }
  __syncthreads();

  // ---------- PV from prefetched vreg ------------------------------------
  {
    float acc[NRR];
#pragma unroll
    for (int r = 0; r < NRR; ++r) acc[r] = 0.f;
#pragma unroll
    for (int j = 0; j < 15; ++j) {
      const int k = kspv + 32 * j;
      const float v = vreg[j];
#pragma unroll
      for (int r = 0; r < NRR; ++r) acc[r] += Sb[r][k] * v;
    }
    if (kspv < NKK - 480) {                   // guarded: avoid -inf*0 NaN
      const int k = kspv + 480;
      const float v = vreg[15];
#pragma unroll
      for (int r = 0; r < NRR; ++r) acc[r] += Sb[r][k] * v;
    }
#pragma unroll
    for (int r = 0; r < NRR; ++r) buf[(kspv * NRR + r) * HD + dpv] = acc[r];
  }
  __syncthreads();
  if (t < 256) {
    const int r = t >> 5, d = t & 31;
    float s = 0.f;
#pragma unroll
    for (int ks = 0; ks < 32; ++ks) s += buf[(ks * NRR + r) * HD + d];
    xs[r][d] = s;
  }
  __syncthreads();

  // ---------- qm partial: slab store (no atomics) or atomicAdd -----------
  {
    const int j = t & 255, rr = t >> 8;
    const int r0 = rr * 2;
    float a0 = 0.f, a1 = 0.f;
#pragma unroll 8
    for (int d = 0; d < HD; ++d) {
      const float w = nn_O[((size_t)(a * HD + d)) * HDIM + j];
      a0 += xs[r0][d] * w;
      a1 += xs[r0 + 1][d] * w;
    }
    if (use_slabs) {
      float* slab = qmw + (size_t)a * BTOT * HDIM;
      slab[(size_t)(p * NRR + r0) * HDIM + j] = a0;
      slab[(size_t)(p * NRR + r0 + 1) * HDIM + j] = a1;
    } else {
      atomicAdd(&qmw[(size_t)(p * NRR + r0) * HDIM + j], a0);
      atomicAdd(&qmw[(size_t)(p * NRR + r0 + 1) * HDIM + j], a1);
    }
  }
}

// ===========================================================================
// Kernel 3: additive logits.  Grid 64 x 32.  Wave owns 4 k; lane owns 4 h.
// qb = nn_B + sum of qm slabs (or single qm).  Mask dtype from ws flag.
// ===========================================================================
__global__ __launch_bounds__(256) void k_logits4(
    const float* __restrict__ X, const float* __restrict__ varfeat,
    const float* __restrict__ nn_A, const float* __restrict__ nn_B,
    const float* __restrict__ nn_W, const float* __restrict__ qmw,
    int use_slabs, const int* __restrict__ flagp,
    const void* __restrict__ maskp, float* __restrict__ ls)
{
  const int p  = blockIdx.x >> 5;
  const int kt = blockIdx.x & 31;
  const int t = threadIdx.x;
  const int wave = t >> 6, lane = t & 63;
  const int h0 = lane * 4;

  __shared__ float As[VDIM][260];
  __shared__ float Ws[HDIM];
  __shared__ float qb[NRR][260];

  const unsigned char* mb = (const unsigned char*)maskp;
  const int* mi = (const int*)maskp;

  const int flag = *flagp;

  for (int idx = t; idx < VDIM * HDIM; idx += 256)
    As[idx >> 8][idx & 255] = nn_A[idx];
  Ws[t] = nn_W[t];
  for (int idx = t; idx < NRR * HDIM; idx += 256) {
    const int r = idx >> 8, h = idx & 255;
    float q;
    if (use_slabs) {
      q = 0.f;
#pragma unroll
      for (int a = 0; a < NHEAD; ++a)
        q += qmw[(size_t)a * BTOT * HDIM + (size_t)(p * NRR + r) * HDIM + h];
    } else {
      q = qmw[(size_t)(p * NRR + r) * HDIM + h];
    }
    qb[r][h] = q + nn_B[h];
  }
  __syncthreads();
  const bool mbyte = (flag != 0);

  const float4 w4 = *reinterpret_cast<const float4*>(&Ws[h0]);

  for (int kk = 0; kk < 4; ++kk) {
    const int k = kt * 16 + wave * 4 + kk;
    if (k >= NKK) break;   // wave-uniform

    const float4 x4 = *reinterpret_cast<const float4*>(
        X + ((size_t)p * NKK + k) * HDIM + h0);
    float base0 = x4.x, base1 = x4.y, base2 = x4.z, base3 = x4.w;
#pragma unroll
    for (int v = 0; v < VDIM; ++v) {
      const float vv = varfeat[((size_t)p * VDIM + v) * NKK + k];
      const float4 a4 = *reinterpret_cast<const float4*>(&As[v][h0]);
      base0 += vv * a4.x; base1 += vv * a4.y;
      base2 += vv * a4.z; base3 += vv * a4.w;
    }

    float acc[NRR];
#pragma unroll
    for (int r = 0; r < NRR; ++r) {
      const float4 q4 = *reinterpret_cast<const float4*>(&qb[r][h0]);
      acc[r] = fast_tanh(base0 + q4.x) * w4.x + fast_tanh(base1 + q4.y) * w4.y
             + fast_tanh(base2 + q4.z) * w4.z + fast_tanh(base3 + q4.w) * w4.w;
    }

    // multi-value wave reduction: 8 sums across 64 lanes
    float v4[4];
    {
      float sw[8];
#pragma unroll
      for (int j = 0; j < 8; ++j) sw[j] = __shfl_xor(acc[j], 32, 64);
      const bool hi = (lane & 32) != 0;
#pragma unroll
      for (int j = 0; j < 4; ++j)
        v4[j] = hi ? (acc[j + 4] + sw[j + 4]) : (acc[j] + sw[j]);
    }
    float v2[2];
    {
      float sw[4];
#pragma unroll
      for (int j = 0; j < 4; ++j) sw[j] = __shfl_xor(v4[j], 16, 64);
      const bool hi = (lane & 16) != 0;
      v2[0] = hi ? (v4[2] + sw[2]) : (v4[0] + sw[0]);
      v2[1] = hi ? (v4[3] + sw[3]) : (v4[1] + sw[1]);
    }
    float w;
    {
      const float s0 = __shfl_xor(v2[0], 8, 64);
      const float s1 = __shfl_xor(v2[1], 8, 64);
      w = ((lane & 8) != 0) ? (v2[1] + s1) : (v2[0] + s0);
    }
    w += __shfl_xor(w, 4, 64);
    w += __shfl_xor(w, 2, 64);
    w += __shfl_xor(w, 1, 64);

    if ((lane & 7) == 0) {
      const int r = lane >> 3;
      const size_t mrow = (size_t)(p * NRR + r) * NKK + k;
      const bool mk = mbyte ? (mb[mrow] != 0) : (mi[mrow] != 0);
      ls[mrow] = mk ? -INFINITY : fast_tanh(w) * 10.0f;
    }
  }
}

// ===========================================================================
// Kernel 4: choose.  One wave per batch row.
// ===========================================================================
__global__ __launch_bounds__(64) void k_choose(
    const float* __restrict__ ls, float* __restrict__ out_p)
{
  const int b = blockIdx.x;
  const int lane = threadIdx.x;
  float m = -INFINITY;
  float lv[8];
  int n = 0;
  for (int k = lane; k < NKK; k += 64, ++n) {
    lv[n] = ls[(size_t)b * NKK + k];
    m = fmaxf(m, lv[n]);
  }
#pragma unroll
  for (int off = 32; off > 0; off >>= 1) m = fmaxf(m, __shfl_xor(m, off, 64));
  float s = 0.f;
  for (int i = 0; i < n; ++i) s += __expf(lv[i] - m);
#pragma unroll
  for (int off = 32; off > 0; off >>= 1) s += __shfl_xor(s, off, 64);
  if (lane == 0) out_p[b] = -logf(s);
}

// ===========================================================================
// Fallback (ws too small): fused kernel — known-correct.
// ===========================================================================
__global__ __launch_bounds__(256) void k_fused(
    const float* __restrict__ X, const float* __restrict__ Kt,
    const float* __restrict__ Vt, const float* __restrict__ varfeat,
    const void* __restrict__ maskp,
    const float* __restrict__ nn_Q, const float* __restrict__ nn_O,
    const float* __restrict__ nn_A, const float* __restrict__ nn_B,
    const float* __restrict__ nn_W,
    const float* __restrict__ out_h, float* __restrict__ out_p)
{
  const int p = blockIdx.x >> 3;
  const int r = blockIdx.x & 7;
  const int t = threadIdx.x;
  const int wave = t >> 6, lane = t & 63;

  __shared__ float hs[HDIM];
  __shared__ float Qs[NHEAD][HD];
  __shared__ float Sb[NHEAD][NKK];
  __shared__ float xs[HDIM];
  __shared__ float qs[HDIM];
  __shared__ float As2[HDIM][VDIM];
  __shared__ float Ws[HDIM];
  __shared__ float lsb[NKK];
  __shared__ int   mask_any;

  const unsigned char* mb = (const unsigned char*)maskp;
  if (t == 0) mask_any = 0;
  __syncthreads();
  {
    int any = 0;
    for (int j = t; j < 2048; j += 256) any |= mb[2 * j + 1];
    if (any) atomicOr(&mask_any, 1);
  }
  for (int idx = t; idx < VDIM * HDIM; idx += 256)
    As2[idx & 255][idx >> 8] = nn_A[idx];
  Ws[t] = nn_W[t];
  hs[t] = out_h[(size_t)(p * NRR + r) * HDIM + t];
  __syncthreads();
  const bool mbyte = (mask_any != 0);
  const int* mi = (const int*)maskp;
  const size_t mrow = (size_t)(p * NRR + r) * NKK;
  {
    const int a = t >> 5, d = t & 31;
    const float* nq = nn_Q + (size_t)a * HDIM * HD + d;
    float acc = 0.f;
    for (int h = 0; h < HDIM; ++h) acc += hs[h] * nq[(size_t)h * HD];
    Qs[a][d] = acc * 0.17677669529663687f;
  }
  __syncthreads();
  for (int k = t; k < NKK; k += 256) {
    const bool mk = mbyte ? (mb[mrow + k] != 0) : (mi[mrow + k] != 0);
#pragma unroll
    for (int a = 0; a < NHEAD; ++a) {
      const float4* kr4 = reinterpret_cast<const float4*>(
          Kt + (((size_t)a * NPP + p) * NKK + k) * HD);
      float s = 0.f;
#pragma unroll
      for (int d4 = 0; d4 < HD / 4; ++d4) {
        const float4 u = kr4[d4];
        s += Qs[a][4 * d4] * u.x + Qs[a][4 * d4 + 1] * u.y
           + Qs[a][4 * d4 + 2] * u.z + Qs[a][4 * d4 + 3] * u.w;
      }
      Sb[a][k] = mk ? -INFINITY : s;
    }
  }
  __syncthreads();
  for (int aa = 0; aa < 2; ++aa) {
    const int a = wave * 2 + aa;
    float m = -INFINITY;
    for (int k = lane; k < NKK; k += 64) m = fmaxf(m, Sb[a][k]);
#pragma unroll
    for (int off = 32; off > 0; off >>= 1) m = fmaxf(m, __shfl_xor(m, off, 64));
    float ssum = 0.f;
    for (int k = lane; k < NKK; k += 64) {
      const float e = expf(Sb[a][k] - m);
      Sb[a][k] = e; ssum += e;
    }
#pragma unroll
    for (int off = 32; off > 0; off >>= 1) ssum += __shfl_xor(ssum, off, 64);
    const float inv = 1.f / ssum;
    for (int k = lane; k < NKK; k += 64) Sb[a][k] *= inv;
  }
  __syncthreads();
  {
    const int a = t >> 5, d = t & 31;
    const float* vb = Vt + ((size_t)a * NPP + p) * NKK * HD + d;
    float acc = 0.f;
    for (int k = 0; k < NKK; ++k) acc += Sb[a][k] * vb[(size_t)k * HD];
    xs[a * HD + d] = acc;
  }
  __syncthreads();
  {
    float acc = 0.f;
    for (int i = 0; i < HDIM; ++i) acc += xs[i] * nn_O[(size_t)i * HDIM + t];
    qs[t] = acc + nn_B[t];
  }
  __syncthreads();
  for (int k = t; k < NKK; k += 256) {
    float vfv[VDIM];
#pragma unroll
    for (int v = 0; v < VDIM; ++v)
      vfv[v] = varfeat[((size_t)p * VDIM + v) * NKK + k];
    const float4* xp4 = reinterpret_cast<const float4*>(
        X + ((size_t)p * NKK + k) * HDIM);
    float acc = 0.f;
    for (int h4 = 0; h4 < HDIM / 4; ++h4) {
      const float4 ux = xp4[h4];
      const float xv[4] = {ux.x, ux.y, ux.z, ux.w};
#pragma unroll
      for (int j = 0; j < 4; ++j) {
        const int h = 4 * h4 + j;
        float base = xv[j] + qs[h];
        const float4 a0 = *reinterpret_cast<const float4*>(&As2[h][0]);
        const float4 a1 = *reinterpret_cast<const float4*>(&As2[h][4]);
        base += vfv[0] * a0.x + vfv[1] * a0.y + vfv[2] * a0.z + vfv[3] * a0.w
              + vfv[4] * a1.x + vfv[5] * a1.y + vfv[6] * a1.z + vfv[7] * a1.w;
        acc += tanhf(base) * Ws[h];
      }
    }
    lsb[k] = acc;
  }
  __syncthreads();
  for (int k = t; k < NKK; k += 256) {
    const bool mk = mbyte ? (mb[mrow + k] != 0) : (mi[mrow + k] != 0);
    lsb[k] = mk ? -INFINITY : tanhf(lsb[k]) * 10.0f;
  }
  __syncthreads();
  if (wave == 0) {
    float m = -INFINITY;
    for (int k = lane; k < NKK; k += 64) m = fmaxf(m, lsb[k]);
#pragma unroll
    for (int off = 32; off > 0; off >>= 1) m = fmaxf(m, __shfl_xor(m, off, 64));
    float s = 0.f;
    for (int k = lane; k < NKK; k += 64) s += expf(lsb[k] - m);
#pragma unroll
    for (int off = 32; off > 0; off >>= 1) s += __shfl_xor(s, off, 64);
    if (lane == 0) out_p[p * NRR + r] = -logf(s);
  }
}

// ===========================================================================
extern "C" void kernel_launch(void* const* d_in, const int* in_sizes, int n_in,
                              void* d_out, int out_size, void* d_ws, size_t ws_size,
                              hipStream_t stream)
{
  const float* X       = (const float*)d_in[0];
  const float* Kt      = (const float*)d_in[1];
  const float* Vt      = (const float*)d_in[2];
  const float* query   = (const float*)d_in[3];
  const float* state1  = (const float*)d_in[4];
  const float* state2  = (const float*)d_in[5];
  const float* varfeat = (const float*)d_in[6];
  const void*  maskp   = d_in[7];
  const float* nn_Q    = (const float*)d_in[8];
  const float* nn_O    = (const float*)d_in[9];
  const float* nn_A    = (const float*)d_in[10];
  const float* nn_B    = (const float*)d_in[11];
  const float* nn_W    = (const float*)d_in[12];
  const float* W_ih    = (const float*)d_in[13];
  const float* W_hh    = (const float*)d_in[14];
  const float* b_ih    = (const float*)d_in[15];
  const float* b_hh    = (const float*)d_in[16];

  float* out   = (float*)d_out;
  float* out_h = out;
  float* out_c = out + (size_t)BTOT * HDIM;
  float* out_p = out + (size_t)2 * BTOT * HDIM;

  const size_t flag_bytes = 256;                              // aligned pad
  const size_t qm1_bytes  = (size_t)BTOT * HDIM * 4;          // 512 KB
  const size_t qm8_bytes  = (size_t)NHEAD * BTOT * HDIM * 4;  // 4 MB
  const size_t ls_bytes   = (size_t)BTOT * NKK * 4;           // 1 MB

  const bool slabs  = ws_size >= flag_bytes + qm8_bytes + ls_bytes;
  const bool atomic = !slabs && ws_size >= flag_bytes + qm1_bytes + ls_bytes;
  int* flagp = (slabs || atomic) ? (int*)d_ws : nullptr;

  hipLaunchKernelGGL(k_lstm3, dim3(32, 16), dim3(256), 0, stream,
                     query, state1, state2, W_ih, W_hh, b_ih, b_hh,
                     (const unsigned char*)maskp, flagp, out_h, out_c);

  if (slabs || atomic) {
    float* qmw = (float*)((char*)d_ws + flag_bytes);
    float* lsw = (float*)((char*)d_ws + flag_bytes +
                          (slabs ? qm8_bytes : qm1_bytes));
    const int use_slabs = slabs ? 1 : 0;
    if (!slabs) hipMemsetAsync(qmw, 0, qm1_bytes, stream);
    hipLaunchKernelGGL(k_attn6, dim3(NPP * NHEAD), dim3(1024), 0, stream,
                       Kt, Vt, nn_Q, nn_O, maskp, flagp, out_h, qmw, use_slabs);
    hipLaunchKernelGGL(k_logits4, dim3(NPP * 32), dim3(256), 0, stream,
                       X, varfeat, nn_A, nn_B, nn_W, qmw, use_slabs, flagp,
                       maskp, lsw);
    hipLaunchKernelGGL(k_choose, dim3(BTOT), dim3(64), 0, stream,
                       lsw, out_p);
  } else {
    hipLaunchKernelGGL(k_fused, dim3(NPP * NRR), dim3(256), 0, stream,
                       X, Kt, Vt, varfeat, maskp,
                       nn_Q, nn_O, nn_A, nn_B, nn_W,
                       out_h, out_p);
  }
}